// Round 12
// baseline (90.996 us; speedup 1.0000x reference)
//
#include <hip/hip_runtime.h>
#include <hip/hip_bf16.h>
#include <cstdint>
#include <cstddef>

#define B_ 2
#define N_ 2048
#define D_ 256
#define H_ 8
#define HID_ 64
#define EN_ 2
#define ALPHA 0.2f
#define NEGBIG (-3.0e38f)
#define LOG2E 1.4426950408889634f

typedef __bf16 bf16x8 __attribute__((ext_vector_type(8)));
typedef float f32x4 __attribute__((ext_vector_type(4)));
typedef unsigned short ushort8 __attribute__((ext_vector_type(8)));
typedef float float4v __attribute__((ext_vector_type(4)));
typedef float float2v __attribute__((ext_vector_type(2)));
typedef unsigned int uint2v __attribute__((ext_vector_type(2)));
typedef unsigned int uint4v __attribute__((ext_vector_type(4)));

__device__ __forceinline__ unsigned short f2bf(float f) {
    unsigned int u = __builtin_bit_cast(unsigned int, f);
    unsigned int r = u + 0x7FFFu + ((u >> 16) & 1u);  // RNE
    return (unsigned short)(r >> 16);
}
__device__ __forceinline__ float bf2f(unsigned short u) {
    unsigned int x = ((unsigned int)u) << 16;
    return __builtin_bit_cast(float, x);
}
__device__ __forceinline__ float leakyf(float x) { return fmaxf(x, ALPHA * x); }
__device__ __forceinline__ float ub(unsigned int d, int e) {
    return (float)((d >> (8 * e)) & 0xffu);
}

__device__ __forceinline__ ushort8 cvt8(const float* __restrict__ p) {
    float4v x0 = *(const float4v*)p;
    float4v x1 = *(const float4v*)(p + 4);
    ushort8 r;
    #pragma unroll
    for (int e = 0; e < 4; ++e) { r[e] = f2bf(x0[e]); r[e + 4] = f2bf(x1[e]); }
    return r;
}

// ---------- K-1: adj f32 -> u8 (exact 0/1) ----------
__global__ __launch_bounds__(256) void k_prep(const float* __restrict__ adj,
                                              unsigned char* __restrict__ adj8) {
    size_t base = ((size_t)blockIdx.x * 256 + threadIdx.x) * 8;
    float4v a = *(const float4v*)(adj + base);
    float4v b = *(const float4v*)(adj + base + 4);
    unsigned int lo = 0, hi = 0;
    #pragma unroll
    for (int e = 0; e < 4; ++e) {
        lo |= (a[e] != 0.f ? 1u : 0u) << (8 * e);
        hi |= (b[e] != 0.f ? 1u : 0u) << (8 * e);
    }
    uint2v o; o[0] = lo; o[1] = hi;
    *(uint2v*)(adj8 + base) = o;
}

// ---------- K0: transpose W_att -> WT bf16 (tiny) ----------
__global__ void k_transpose_w(const float* __restrict__ W,
                              unsigned short* __restrict__ WT) {
    int h = blockIdx.x;
    const float* Wh = W + (size_t)h * D_ * HID_;
    unsigned short* WTh = WT + (size_t)h * HID_ * D_;
    for (int idx = threadIdx.x; idx < D_ * HID_; idx += blockDim.x) {
        int d = idx / HID_, o = idx % HID_;
        WTh[o * D_ + d] = f2bf(Wh[idx]);
    }
}

// ---------- K1: wh = fea @ W_att, 2 heads per block ----------
__global__ __launch_bounds__(256) void k_wh(
    const float* __restrict__ fea,
    const unsigned short* __restrict__ WT,
    const float* __restrict__ a_att,
    unsigned short* __restrict__ whT,
    float* __restrict__ e1, float* __restrict__ e2)
{
    int i0 = blockIdx.x << 6;
    int h0 = blockIdx.y * 2;
    int b  = blockIdx.z;

    __shared__ __align__(16) union SmemA {
        struct { unsigned short fa[64 * 72]; unsigned short wt[2][64 * 72]; } s;
        float tr[64 * 65];
    } u;

    int t = threadIdx.x;
    int lane = t & 63;
    int wv = t >> 6;
    int hw = wv & 1;
    int half = wv >> 1;
    int r = lane & 15, q = lane >> 4;
    int ra = t >> 2;
    int cc = (t & 3) * 16;
    int rowbase = half * 32;

    f32x4 acc[2][4] = {};

    const float* fearow = fea + ((size_t)(b * N_ + i0 + ra)) * D_;
    const unsigned short* wt0row = WT + ((size_t)(h0 * 64 + ra)) * D_;
    const unsigned short* wt1row = WT + ((size_t)((h0 + 1) * 64 + ra)) * D_;

    for (int d0 = 0; d0 < D_; d0 += 64) {
        *(ushort8*)&u.s.fa[ra * 72 + cc]       = cvt8(fearow + d0 + cc);
        *(ushort8*)&u.s.fa[ra * 72 + cc + 8]   = cvt8(fearow + d0 + cc + 8);
        *(ushort8*)&u.s.wt[0][ra * 72 + cc]     = *(const ushort8*)(wt0row + d0 + cc);
        *(ushort8*)&u.s.wt[0][ra * 72 + cc + 8] = *(const ushort8*)(wt0row + d0 + cc + 8);
        *(ushort8*)&u.s.wt[1][ra * 72 + cc]     = *(const ushort8*)(wt1row + d0 + cc);
        *(ushort8*)&u.s.wt[1][ra * 72 + cc + 8] = *(const ushort8*)(wt1row + d0 + cc + 8);
        __syncthreads();
        #pragma unroll
        for (int k0 = 0; k0 < 64; k0 += 32) {
            bf16x8 a0 = *(const bf16x8*)&u.s.fa[(rowbase + r) * 72 + k0 + q * 8];
            bf16x8 a1 = *(const bf16x8*)&u.s.fa[(rowbase + 16 + r) * 72 + k0 + q * 8];
            #pragma unroll
            for (int f = 0; f < 4; ++f) {
                bf16x8 bb = *(const bf16x8*)&u.s.wt[hw][(16 * f + r) * 72 + k0 + q * 8];
                acc[0][f] = __builtin_amdgcn_mfma_f32_16x16x32_bf16(a0, bb, acc[0][f], 0, 0, 0);
                acc[1][f] = __builtin_amdgcn_mfma_f32_16x16x32_bf16(a1, bb, acc[1][f], 0, 0, 0);
            }
        }
        __syncthreads();
    }

    float a1v[4], a2v[4];
    #pragma unroll
    for (int f = 0; f < 4; ++f) {
        a1v[f] = a_att[(h0 + hw) * 128 + 16 * f + r];
        a2v[f] = a_att[(h0 + hw) * 128 + 64 + 16 * f + r];
    }
    #pragma unroll
    for (int m = 0; m < 2; ++m) {
        #pragma unroll
        for (int rr = 0; rr < 4; ++rr) {
            float s1 = 0.f, s2 = 0.f;
            #pragma unroll
            for (int f = 0; f < 4; ++f) { s1 += acc[m][f][rr] * a1v[f]; s2 += acc[m][f][rr] * a2v[f]; }
            #pragma unroll
            for (int sh = 1; sh < 16; sh <<= 1) {
                s1 += __shfl_xor(s1, sh, 64);
                s2 += __shfl_xor(s2, sh, 64);
            }
            if (r == 0) {
                int i = i0 + rowbase + 16 * m + 4 * q + rr;
                size_t idx = ((size_t)(b * H_ + h0 + hw)) * N_ + i;
                e1[idx] = s1 * LOG2E; e2[idx] = s2 * LOG2E;
            }
        }
    }

    #pragma unroll
    for (int hh = 0; hh < 2; ++hh) {
        __syncthreads();
        if (hw == hh) {
            #pragma unroll
            for (int m = 0; m < 2; ++m)
                #pragma unroll
                for (int f = 0; f < 4; ++f)
                    #pragma unroll
                    for (int rr = 0; rr < 4; ++rr)
                        u.tr[(16 * f + r) * 65 + rowbase + 16 * m + 4 * q + rr] = acc[m][f][rr];
        }
        __syncthreads();
        {
            int o = t >> 2;
            int ch = (t & 3) * 16;
            unsigned short tmp[16];
            #pragma unroll
            for (int e = 0; e < 16; ++e) tmp[e] = f2bf(u.tr[o * 65 + ch + e]);
            ushort8* dst = (ushort8*)(whT + (((size_t)(b * H_ + h0 + hh) * 64 + o)) * N_ + i0 + ch);
            dst[0] = *(ushort8*)&tmp[0];
            dst[1] = *(ushort8*)&tmp[8];
        }
    }
}

// ---------- K2: maxE2[bh] = max_j e2[bh][j] ----------
__global__ __launch_bounds__(256) void k_maxe2(const float* __restrict__ e2,
                                               float* __restrict__ mx) {
    int bh = blockIdx.x;
    int t = threadIdx.x;
    const float* row = e2 + (size_t)bh * N_;
    float M = NEGBIG;
    #pragma unroll
    for (int it = 0; it < N_ / 256; ++it) M = fmaxf(M, row[it * 256 + t]);
    #pragma unroll
    for (int s = 1; s < 64; s <<= 1) M = fmaxf(M, __shfl_xor(M, s, 64));
    __shared__ float red[4];
    if ((t & 63) == 0) red[t >> 6] = M;
    __syncthreads();
    if (t == 0) mx[bh] = fmaxf(fmaxf(red[0], red[1]), fmaxf(red[2], red[3]));
}

// ---------- K3 (new): 2 heads x 128 rows per 512-thr block; adj via LDS ----------
// VMEM-issue-minimized: per thread per tile: 2x b128 whT + 1x b128 adj loads;
// epilogue via LDS transpose -> 4x b128 stores/thread.
template<int JPER>
__global__ __launch_bounds__(512, 4) void k_pv2(
    const unsigned char* __restrict__ adj8,
    const unsigned short* __restrict__ whT,   // [B][H][64][N] bf16
    const float* __restrict__ e1g, const float* __restrict__ e2g,
    const float* __restrict__ maxE2,
    unsigned short* __restrict__ x_part,      // [S][B][N][512] bf16
    float* __restrict__ zPart)                // [S][16][N] f32
{
    constexpr int NT = JPER / 64;
    int s  = blockIdx.x;
    int i0 = blockIdx.y << 7;                 // 128 rows
    int z  = blockIdx.z;                      // b*4 + hpair
    int b  = z >> 2;
    int h0 = (z & 3) * 2;
    int bh0 = b * H_ + h0;
    int jBeg = s * JPER;

    __shared__ __align__(16) union {
        struct {
            unsigned short wt[2][2][4096];    // [buf][head][64x64] swizzled
            unsigned char  adjl[2][128 * 80]; // [buf][row][80-pad]
            unsigned int   tv[2][JPER];       // packed bf16 {2^e2, 2^(a*e2)}
        } m;
        unsigned short epi[128][136];
    } u;

    int t = threadIdx.x;
    int lane = t & 63;
    int w = t >> 6;                           // wave 0..7
    int hw = w & 1;                           // head within pair
    int rw = (w >> 1) * 32;                   // row base of this wave
    int r = lane & 15, q = lane >> 4;
    int bh = bh0 + hw;

    // per-row softmax prefactors (2 rows per lane)
    int ir0 = i0 + rw + r, ir1 = ir0 + 16;
    float mxv = maxE2[bh];
    float e1_0 = e1g[(size_t)bh * N_ + ir0];
    float e1_1 = e1g[(size_t)bh * N_ + ir1];
    float m0 = leakyf(e1_0 + mxv), m1 = leakyf(e1_1 + mxv);
    float sI0 = __builtin_amdgcn_exp2f(e1_0 - m0);
    float uI0 = __builtin_amdgcn_exp2f(ALPHA * e1_0 - m0);
    float sI1 = __builtin_amdgcn_exp2f(e1_1 - m1);
    float uI1 = __builtin_amdgcn_exp2f(ALPHA * e1_1 - m1);

    // staging assignments
    int sh = t >> 8;                          // head this thread stages
    int so = (t & 255) >> 2;                  // o-row
    int sj = (t & 3) * 16;                    // j-col chunk
    const unsigned short* wsrc = whT + ((size_t)(bh0 + sh) * 64 + so) * N_ + jBeg + sj;
    int wof0 = sh * 4096 + so * 64 + (sj ^ ((so & 7) << 3));
    int wof1 = sh * 4096 + so * 64 + ((sj + 8) ^ ((so & 7) << 3));
    int ar = t >> 2, ac = (t & 3) * 16;
    const unsigned char* asrc = adj8 + ((size_t)(b * N_ + i0 + ar)) * N_ + jBeg + ac;
    int aof = ar * 80 + ac;

    int swzr = (r & 7) << 3;
    int koff0 = (8 * q) ^ swzr;
    int koff1 = (32 + 8 * q) ^ swzr;

    bf16x8 ones;
    #pragma unroll
    for (int e = 0; e < 8; ++e) ones[e] = (__bf16)1.0f;

    f32x4 acc[2][4] = {};
    f32x4 accz[2] = {};

    ushort8 wA, wB;   // whT stage regs (1 tile ahead)
    uint4v  aR;       // adj stage reg

#define LOADSTG(tile) do {                                        \
        wA = *(const ushort8*)(wsrc + (tile) * 64);               \
        wB = *(const ushort8*)(wsrc + (tile) * 64 + 8);           \
        aR = *(const uint4v*)(asrc + (tile) * 64);                \
    } while (0)

    // prologue: tv tables, tile0 -> buf0, tile1 -> regs
    for (int jj = t; jj < 2 * JPER; jj += 512) {
        int hh = jj >= JPER ? 1 : 0;
        int j = jj - hh * JPER;
        float ev = e2g[(size_t)(bh0 + hh) * N_ + jBeg + j];
        unsigned int pk = (unsigned int)f2bf(__builtin_amdgcn_exp2f(ev))
                        | ((unsigned int)f2bf(__builtin_amdgcn_exp2f(ALPHA * ev)) << 16);
        u.m.tv[hh][j] = pk;
    }
    LOADSTG(0);
    asm volatile("s_waitcnt vmcnt(0)" ::: "memory");
    *(ushort8*)((unsigned short*)u.m.wt[0] + wof0) = wA;
    *(ushort8*)((unsigned short*)u.m.wt[0] + wof1) = wB;
    *(uint4v*)&u.m.adjl[0][aof] = aR;
    if (NT > 1) LOADSTG(1);
    asm volatile("s_waitcnt lgkmcnt(0)" ::: "memory");
    __builtin_amdgcn_s_barrier();

    #pragma unroll 2
    for (int t8 = 0; t8 < NT; ++t8) {
        const int p = t8 & 1;
        // write tile t8+1 (regs) into other buffer; then prefetch t8+2
        if (t8 + 1 < NT) {
            asm volatile("s_waitcnt vmcnt(0)" ::: "memory");
            *(ushort8*)((unsigned short*)u.m.wt[p ^ 1] + wof0) = wA;
            *(ushort8*)((unsigned short*)u.m.wt[p ^ 1] + wof1) = wB;
            *(uint4v*)&u.m.adjl[p ^ 1][aof] = aR;
        }
        if (t8 + 2 < NT) LOADSTG(t8 + 2);

        // tv slices (bf16-packed), shared by both m-rows
        const unsigned int* tvp = &u.m.tv[hw][t8 * 64 + q * 8];
        uint4v ta0 = *(const uint4v*)(tvp);
        uint4v ta1 = *(const uint4v*)(tvp + 4);
        uint4v tb0 = *(const uint4v*)(tvp + 32);
        uint4v tb1 = *(const uint4v*)(tvp + 36);
        // adj bytes from LDS (2 rows x 2 k-halves)
        const unsigned char* ab = &u.m.adjl[p][(rw + r) * 80 + q * 8];
        uint2v a0 = *(const uint2v*)(ab);
        uint2v a1 = *(const uint2v*)(ab + 32);
        uint2v a2 = *(const uint2v*)(ab + 16 * 80);
        uint2v a3 = *(const uint2v*)(ab + 16 * 80 + 32);

        bf16x8 pa00, pa01, pa10, pa11;
        #pragma unroll
        for (int e = 0; e < 4; ++e) {
            float tt, vv;
            unsigned int uu;
            uu = ta0[e];
            tt = __builtin_bit_cast(float, uu << 16);
            vv = __builtin_bit_cast(float, uu & 0xffff0000u);
            pa00[e] = (__bf16)(fmaxf(sI0 * tt, uI0 * vv) * ub(a0[0], e));
            pa10[e] = (__bf16)(fmaxf(sI1 * tt, uI1 * vv) * ub(a2[0], e));
            uu = ta1[e];
            tt = __builtin_bit_cast(float, uu << 16);
            vv = __builtin_bit_cast(float, uu & 0xffff0000u);
            pa00[e + 4] = (__bf16)(fmaxf(sI0 * tt, uI0 * vv) * ub(a0[1], e));
            pa10[e + 4] = (__bf16)(fmaxf(sI1 * tt, uI1 * vv) * ub(a2[1], e));
            uu = tb0[e];
            tt = __builtin_bit_cast(float, uu << 16);
            vv = __builtin_bit_cast(float, uu & 0xffff0000u);
            pa01[e] = (__bf16)(fmaxf(sI0 * tt, uI0 * vv) * ub(a1[0], e));
            pa11[e] = (__bf16)(fmaxf(sI1 * tt, uI1 * vv) * ub(a3[0], e));
            uu = tb1[e];
            tt = __builtin_bit_cast(float, uu << 16);
            vv = __builtin_bit_cast(float, uu & 0xffff0000u);
            pa01[e + 4] = (__bf16)(fmaxf(sI0 * tt, uI0 * vv) * ub(a1[1], e));
            pa11[e + 4] = (__bf16)(fmaxf(sI1 * tt, uI1 * vv) * ub(a3[1], e));
        }

        const unsigned short* Wb = (const unsigned short*)u.m.wt[p] + hw * 4096;
        bf16x8 bb;
        #pragma unroll
        for (int f = 0; f < 4; ++f) {
            bb = *(const bf16x8*)&Wb[f * 1024 + r * 64 + koff0];
            acc[0][f] = __builtin_amdgcn_mfma_f32_16x16x32_bf16(pa00, bb, acc[0][f], 0, 0, 0);
            acc[1][f] = __builtin_amdgcn_mfma_f32_16x16x32_bf16(pa10, bb, acc[1][f], 0, 0, 0);
        }
        accz[0] = __builtin_amdgcn_mfma_f32_16x16x32_bf16(pa00, ones, accz[0], 0, 0, 0);
        accz[1] = __builtin_amdgcn_mfma_f32_16x16x32_bf16(pa10, ones, accz[1], 0, 0, 0);
        #pragma unroll
        for (int f = 0; f < 4; ++f) {
            bb = *(const bf16x8*)&Wb[f * 1024 + r * 64 + koff1];
            acc[0][f] = __builtin_amdgcn_mfma_f32_16x16x32_bf16(pa01, bb, acc[0][f], 0, 0, 0);
            acc[1][f] = __builtin_amdgcn_mfma_f32_16x16x32_bf16(pa11, bb, acc[1][f], 0, 0, 0);
        }
        accz[0] = __builtin_amdgcn_mfma_f32_16x16x32_bf16(pa01, ones, accz[0], 0, 0, 0);
        accz[1] = __builtin_amdgcn_mfma_f32_16x16x32_bf16(pa11, ones, accz[1], 0, 0, 0);

        asm volatile("s_waitcnt lgkmcnt(0)" ::: "memory");
        __builtin_amdgcn_s_barrier();
    }
#undef LOADSTG

    // zPart (small, direct)
    if (r == 0) {
        #pragma unroll
        for (int mR = 0; mR < 2; ++mR)
            #pragma unroll
            for (int rr = 0; rr < 4; ++rr) {
                int i = i0 + rw + mR * 16 + 4 * q + rr;
                zPart[((size_t)(s * 16 + bh)) * N_ + i] = accz[mR][rr];
            }
    }

    // epilogue: acc -> LDS (bf16) -> coalesced b128 stores
    #pragma unroll
    for (int mR = 0; mR < 2; ++mR)
        #pragma unroll
        for (int f = 0; f < 4; ++f)
            #pragma unroll
            for (int rr = 0; rr < 4; ++rr)
                u.epi[rw + mR * 16 + 4 * q + rr][hw * 64 + 16 * f + r] = f2bf(acc[mR][f][rr]);
    __syncthreads();
    {
        int tr = t >> 2;
        int ch = (t & 3) * 32;
        const ushort8* src = (const ushort8*)&u.epi[tr][ch];
        ushort8 v0 = src[0], v1 = src[1], v2 = src[2], v3 = src[3];
        unsigned short* dst = x_part
            + ((size_t)s * (B_ * N_) + (size_t)b * N_ + i0 + tr) * 512 + h0 * 64 + ch;
        ((ushort8*)dst)[0] = v0;
        ((ushort8*)dst)[1] = v1;
        ((ushort8*)dst)[2] = v2;
        ((ushort8*)dst)[3] = v3;
    }
}

// ---------- K3 (fallback for S<4): round-9 kernel ----------
template<int JPER>
__global__ __launch_bounds__(256, 4) void k_pv1(
    const unsigned char* __restrict__ adj8,
    const unsigned short* __restrict__ whT,
    const float* __restrict__ e1g, const float* __restrict__ e2g,
    const float* __restrict__ maxE2,
    unsigned short* __restrict__ x_part,
    float* __restrict__ zPart)
{
    constexpr int NT = JPER / 64;
    int s  = blockIdx.x;
    int i0 = blockIdx.y << 7;
    int bh = blockIdx.z;
    int h = bh & 7, b = bh >> 3;
    int jBeg = s * JPER;

    __shared__ __align__(16) unsigned short wt_lds[2][64 * 64];
    __shared__ float tE[JPER];
    __shared__ float vE[JPER];

    int t = threadIdx.x;
    int lane = t & 63;
    int wv = t >> 6;
    int r = lane & 15, q = lane >> 4;

    int ir0 = i0 + wv * 32 + r;
    int ir1 = ir0 + 16;
    float mx = maxE2[bh];
    float e1_0 = e1g[(size_t)bh * N_ + ir0];
    float e1_1 = e1g[(size_t)bh * N_ + ir1];
    float m0 = leakyf(e1_0 + mx), m1 = leakyf(e1_1 + mx);
    float sI0 = __builtin_amdgcn_exp2f(e1_0 - m0);
    float uI0 = __builtin_amdgcn_exp2f(ALPHA * e1_0 - m0);
    float sI1 = __builtin_amdgcn_exp2f(e1_1 - m1);
    float uI1 = __builtin_amdgcn_exp2f(ALPHA * e1_1 - m1);

    const float* e2p = e2g + (size_t)bh * N_ + jBeg;
    const unsigned char* ap0 = adj8 + ((size_t)(b * N_ + ir0)) * N_ + jBeg + q * 8;
    const unsigned char* ap1 = ap0 + (size_t)16 * N_;

    int c0 = t, c1 = t + 256;
    const unsigned short* wsrc0 =
        whT + ((size_t)bh * 64 + (c0 >> 3)) * N_ + jBeg + (c0 & 7) * 8;
    const unsigned short* wsrc1 =
        whT + ((size_t)bh * 64 + (c1 >> 3)) * N_ + jBeg + (c1 & 7) * 8;
    int woff0 = (c0 * 8) ^ (((c0 >> 3) & 7) << 3);
    int woff1 = (c1 * 8) ^ (((c1 >> 3) & 7) << 3);

    int swz = (r & 7) << 3;
    int koff0 = (8 * q) ^ swz;
    int koff1 = (32 + 8 * q) ^ swz;

    bf16x8 ones;
    #pragma unroll
    for (int e = 0; e < 8; ++e) ones[e] = (__bf16)1.0f;

    f32x4 acc[2][4] = {};
    f32x4 accz[2] = {};

    uint2v aA[4], aB[4];
    ushort8 wN0, wN1;

#define LOADADJ(A, tile) do {                                                   \
        const unsigned char* p0 = ap0 + (tile) * 64;                            \
        const unsigned char* p1 = ap1 + (tile) * 64;                            \
        A[0] = *(const uint2v*)(p0);      A[1] = *(const uint2v*)(p0 + 32);     \
        A[2] = *(const uint2v*)(p1);      A[3] = *(const uint2v*)(p1 + 32);     \
    } while (0)
#define LOADW(tile) do {                                                        \
        wN0 = *(const ushort8*)(wsrc0 + (tile) * 64);                           \
        wN1 = *(const ushort8*)(wsrc1 + (tile) * 64);                           \
    } while (0)

    for (int jj = t; jj < JPER; jj += 256) {
        float ev = e2p[jj];
        tE[jj] = __builtin_amdgcn_exp2f(ev);
        vE[jj] = __builtin_amdgcn_exp2f(ALPHA * ev);
    }
    LOADW(0);
    *(ushort8*)&wt_lds[0][woff0] = wN0;
    *(ushort8*)&wt_lds[0][woff1] = wN1;
    if (NT > 1) LOADW(1);
    LOADADJ(aA, 0);
    if (NT > 1) LOADADJ(aB, 1);
    asm volatile("s_waitcnt lgkmcnt(0)" ::: "memory");
    __builtin_amdgcn_s_barrier();

    auto pgen = [&](const uint2v& alo, const uint2v& ahi, float sI, float uI,
                    const float4v& t0, const float4v& t1,
                    const float4v& t2, const float4v& t3,
                    const float4v& v0, const float4v& v1,
                    const float4v& v2, const float4v& v3,
                    bf16x8& pa0, bf16x8& pa1) {
        #pragma unroll
        for (int e = 0; e < 4; ++e) {
            pa0[e]     = (__bf16)(fmaxf(sI * t0[e], uI * v0[e]) * ub(alo[0], e));
            pa0[e + 4] = (__bf16)(fmaxf(sI * t1[e], uI * v1[e]) * ub(alo[1], e));
            pa1[e]     = (__bf16)(fmaxf(sI * t2[e], uI * v2[e]) * ub(ahi[0], e));
            pa1[e + 4] = (__bf16)(fmaxf(sI * t3[e], uI * v3[e]) * ub(ahi[1], e));
        }
    };

    #pragma unroll 2
    for (int t8 = 0; t8 < NT; ++t8) {
        const int cur = t8 & 1;
        if (t8 + 1 < NT) {
            *(ushort8*)&wt_lds[cur ^ 1][woff0] = wN0;
            *(ushort8*)&wt_lds[cur ^ 1][woff1] = wN1;
        }
        if (t8 + 2 < NT) LOADW(t8 + 2);

        const float* tb = &tE[t8 * 64 + q * 8];
        const float* vb = &vE[t8 * 64 + q * 8];
        float4v t0 = *(const float4v*)(tb),      t1 = *(const float4v*)(tb + 4);
        float4v t2 = *(const float4v*)(tb + 32), t3 = *(const float4v*)(tb + 36);
        float4v v0 = *(const float4v*)(vb),      v1 = *(const float4v*)(vb + 4);
        float4v v2 = *(const float4v*)(vb + 32), v3 = *(const float4v*)(vb + 36);

        bf16x8 pa00, pa01, pa10, pa11;
        if (cur == 0) {
            pgen(aA[0], aA[1], sI0, uI0, t0, t1, t2, t3, v0, v1, v2, v3, pa00, pa01);
            pgen(aA[2], aA[3], sI1, uI1, t0, t1, t2, t3, v0, v1, v2, v3, pa10, pa11);
        } else {
            pgen(aB[0], aB[1], sI0, uI0, t0, t1, t2, t3, v0, v1, v2, v3, pa00, pa01);
            pgen(aB[2], aB[3], sI1, uI1, t0, t1, t2, t3, v0, v1, v2, v3, pa10, pa11);
        }
        if (t8 + 2 < NT) {
            if (cur == 0) LOADADJ(aA, t8 + 2);
            else          LOADADJ(aB, t8 + 2);
        }

        const unsigned short* Wb = wt_lds[cur];
        bf16x8 bb0[4], bb1[4];
        #pragma unroll
        for (int f = 0; f < 4; ++f) {
            bb0[f] = *(const bf16x8*)&Wb[f * 1024 + r * 64 + koff0];
            bb1[f] = *(const bf16x8*)&Wb[f * 1024 + r * 64 + koff1];
        }
        #pragma unroll
        for (int f = 0; f < 4; ++f) {
            acc[0][f] = __builtin_amdgcn_mfma_f32_16x16x32_bf16(pa00, bb0[f], acc[0][f], 0, 0, 0);
            acc[1][f] = __builtin_amdgcn_mfma_f32_16x16x32_bf16(pa10, bb0[f], acc[1][f], 0, 0, 0);
        }
        accz[0] = __builtin_amdgcn_mfma_f32_16x16x32_bf16(pa00, ones, accz[0], 0, 0, 0);
        accz[1] = __builtin_amdgcn_mfma_f32_16x16x32_bf16(pa10, ones, accz[1], 0, 0, 0);
        #pragma unroll
        for (int f = 0; f < 4; ++f) {
            acc[0][f] = __builtin_amdgcn_mfma_f32_16x16x32_bf16(pa01, bb1[f], acc[0][f], 0, 0, 0);
            acc[1][f] = __builtin_amdgcn_mfma_f32_16x16x32_bf16(pa11, bb1[f], acc[1][f], 0, 0, 0);
        }
        accz[0] = __builtin_amdgcn_mfma_f32_16x16x32_bf16(pa01, ones, accz[0], 0, 0, 0);
        accz[1] = __builtin_amdgcn_mfma_f32_16x16x32_bf16(pa11, ones, accz[1], 0, 0, 0);

        asm volatile("s_waitcnt lgkmcnt(0)" ::: "memory");
        __builtin_amdgcn_s_barrier();
    }
#undef LOADADJ
#undef LOADW

    unsigned short* xp = x_part + ((size_t)s * (B_ * N_) + (size_t)b * N_) * 512 + h * 64;
    #pragma unroll
    for (int mR = 0; mR < 2; ++mR) {
        #pragma unroll
        for (int f = 0; f < 4; ++f) {
            #pragma unroll
            for (int rr = 0; rr < 4; ++rr) {
                int i = i0 + wv * 32 + mR * 16 + 4 * q + rr;
                xp[(size_t)i * 512 + 16 * f + r] = f2bf(acc[mR][f][rr]);
            }
        }
        if (r == 0) {
            #pragma unroll
            for (int rr = 0; rr < 4; ++rr) {
                int i = i0 + wv * 32 + mR * 16 + 4 * q + rr;
                zPart[((size_t)(s * 16 + bh)) * N_ + i] = accz[mR][rr];
            }
        }
    }
}

// ---------- K4: x = elu(sum_s part / Z); wh2 = x @ W_last ----------
__global__ __launch_bounds__(256) void k_wh2(
    const unsigned short* __restrict__ x_part,
    const float* __restrict__ zPart,
    const float* __restrict__ W_last,
    const float* __restrict__ a_last,
    float* __restrict__ wh2, float* __restrict__ g1, float* __restrict__ g2,
    int S)
{
    int idx = blockIdx.x * 4 + (threadIdx.x >> 6);
    int lane = threadIdx.x & 63;
    int b = idx >> 11, n = idx & (N_ - 1);
    float a0 = 0.f, a1 = 0.f;
    #pragma unroll
    for (int it = 0; it < 8; ++it) {
        int k = it * 64 + lane;
        float xv = 0.f, zv = 0.f;
        for (int s = 0; s < S; ++s) {
            xv += bf2f(x_part[((size_t)s * (B_ * N_) + idx) * 512 + k]);
            zv += zPart[((size_t)(s * 16 + b * 8 + it)) * N_ + n];
        }
        float x = (zv > 0.f) ? xv / zv : 0.f;
        x = x > 0.f ? x : expm1f(x);
        float2v wl = *(const float2v*)(W_last + k * 2);
        a0 += x * wl[0];
        a1 += x * wl[1];
    }
    #pragma unroll
    for (int s = 1; s < 64; s <<= 1) {
        a0 += __shfl_xor(a0, s, 64);
        a1 += __shfl_xor(a1, s, 64);
    }
    if (lane == 0) {
        wh2[idx * 2] = a0; wh2[idx * 2 + 1] = a1;
        g1[idx] = (a0 * a_last[0] + a1 * a_last[1]) * LOG2E;
        g2[idx] = (a0 * a_last[2] + a1 * a_last[3]) * LOG2E;
    }
}

// ---------- K5: final attention + elu ----------
__global__ __launch_bounds__(256) void k_out(
    const unsigned char* __restrict__ adj8,
    const float* __restrict__ wh2,
    const float* __restrict__ g1, const float* __restrict__ g2,
    float* __restrict__ out)
{
    int idx = blockIdx.x * 4 + (threadIdx.x >> 6);
    int lane = threadIdx.x & 63;
    int b = idx >> 11;
    float gi = g1[idx];
    const unsigned char* arow = adj8 + (size_t)idx * N_;
    const float* g2b = g2 + (size_t)b * N_;
    const float* wh2b = wh2 + (size_t)b * N_ * 2;

    float ep[32];
    float M = NEGBIG;
    #pragma unroll
    for (int it = 0; it < 8; ++it) {
        int j = it * 256 + lane * 4;
        unsigned int d = *(const unsigned int*)(arow + j);
        float4v s4 = *(const float4v*)(g2b + j);
        #pragma unroll
        for (int e = 0; e < 4; ++e) {
            float l = leakyf(gi + s4[e]);
            float v = ((d >> (8 * e)) & 0xffu) ? l : NEGBIG;
            ep[it * 4 + e] = v;
            M = fmaxf(M, v);
        }
    }
    #pragma unroll
    for (int s = 1; s < 64; s <<= 1) M = fmaxf(M, __shfl_xor(M, s, 64));

    float Z = 0.f, A0 = 0.f, A1 = 0.f;
    #pragma unroll
    for (int it = 0; it < 8; ++it) {
        int j = it * 256 + lane * 4;
        float4v wA = *(const float4v*)(wh2b + 2 * j);
        float4v wB = *(const float4v*)(wh2b + 2 * j + 4);
        #pragma unroll
        for (int e = 0; e < 4; ++e) {
            float p = __builtin_amdgcn_exp2f(ep[it * 4 + e] - M);
            Z += p;
            float w0 = (e < 2) ? wA[2 * e] : wB[2 * (e - 2)];
            float w1 = (e < 2) ? wA[2 * e + 1] : wB[2 * (e - 2) + 1];
            A0 += p * w0;
            A1 += p * w1;
        }
    }
    #pragma unroll
    for (int s = 1; s < 64; s <<= 1) {
        Z += __shfl_xor(Z, s, 64);
        A0 += __shfl_xor(A0, s, 64);
        A1 += __shfl_xor(A1, s, 64);
    }
    if (lane == 0) {
        float o0 = A0 / Z, o1 = A1 / Z;
        o0 = o0 > 0.f ? o0 : expm1f(o0);
        o1 = o1 > 0.f ? o1 : expm1f(o1);
        float2v ov; ov[0] = o0; ov[1] = o1;
        *(float2v*)(out + idx * 2) = ov;
    }
}

extern "C" void kernel_launch(void* const* d_in, const int* in_sizes, int n_in,
                              void* d_out, int out_size, void* d_ws, size_t ws_size,
                              hipStream_t stream) {
    const float* fea    = (const float*)d_in[0];
    const float* adj    = (const float*)d_in[1];
    const float* W_att  = (const float*)d_in[2];
    const float* a_att  = (const float*)d_in[3];
    const float* W_last = (const float*)d_in[4];
    const float* a_last = (const float*)d_in[5];

    char* ws = (char*)d_ws;
    float* e1  = (float*)(ws + 0);
    float* e2  = (float*)(ws + 131072);
    float* mxE = (float*)(ws + 262144);
    float* wh2 = (float*)(ws + 262400);
    float* g1  = (float*)(ws + 295168);
    float* g2  = (float*)(ws + 311552);
    unsigned short* WT  = (unsigned short*)(ws + 327936);
    unsigned short* whT = (unsigned short*)(ws + 590080);
    float* zPart = (float*)(ws + 4784384);
    unsigned char* adj8 = (unsigned char*)(ws + 5308672);
    unsigned short* x_part = (unsigned short*)(ws + 13697280);

    const size_t BASE = 13697280ULL, XPART = 4194304ULL;
    int S = (ws_size >= BASE + 4 * XPART) ? 4
          : (ws_size >= BASE + 2 * XPART) ? 2 : 1;

    k_prep<<<dim3(B_ * N_ * N_ / 2048), dim3(256), 0, stream>>>(adj, adj8);
    k_transpose_w<<<dim3(H_), dim3(256), 0, stream>>>(W_att, WT);
    k_wh<<<dim3(N_ / 64, H_ / 2, B_), dim3(256), 0, stream>>>(
        fea, WT, a_att, whT, e1, e2);
    k_maxe2<<<dim3(B_ * H_), dim3(256), 0, stream>>>(e2, mxE);
    if (S == 4)
        k_pv2<512><<<dim3(4, N_ / 128, B_ * 4), dim3(512), 0, stream>>>(
            adj8, whT, e1, e2, mxE, x_part, zPart);
    else if (S == 2)
        k_pv1<1024><<<dim3(2, N_ / 128, B_ * H_), dim3(256), 0, stream>>>(
            adj8, whT, e1, e2, mxE, x_part, zPart);
    else
        k_pv1<2048><<<dim3(1, N_ / 128, B_ * H_), dim3(256), 0, stream>>>(
            adj8, whT, e1, e2, mxE, x_part, zPart);
    k_wh2<<<dim3(B_ * N_ / 4), dim3(256), 0, stream>>>(
        x_part, zPart, W_last, a_last, wh2, g1, g2, S);
    k_out<<<dim3(B_ * N_ / 4), dim3(256), 0, stream>>>(
        adj8, wh2, g1, g2, (float*)d_out);
}

// Round 13
// 90.955 us; speedup vs baseline: 1.0005x; 1.0005x over previous
//
#include <hip/hip_runtime.h>
#include <hip/hip_bf16.h>
#include <cstdint>
#include <cstddef>

#define B_ 2
#define N_ 2048
#define D_ 256
#define H_ 8
#define HID_ 64
#define EN_ 2
#define ALPHA 0.2f
#define NEGBIG (-3.0e38f)
#define LOG2E 1.4426950408889634f

typedef __bf16 bf16x8 __attribute__((ext_vector_type(8)));
typedef float f32x4 __attribute__((ext_vector_type(4)));
typedef unsigned short ushort8 __attribute__((ext_vector_type(8)));
typedef float float4v __attribute__((ext_vector_type(4)));
typedef float float2v __attribute__((ext_vector_type(2)));
typedef unsigned int uint2v __attribute__((ext_vector_type(2)));
typedef unsigned int uint4v __attribute__((ext_vector_type(4)));

__device__ __forceinline__ unsigned short f2bf(float f) {
    unsigned int u = __builtin_bit_cast(unsigned int, f);
    unsigned int r = u + 0x7FFFu + ((u >> 16) & 1u);  // RNE
    return (unsigned short)(r >> 16);
}
__device__ __forceinline__ float bf2f(unsigned short u) {
    unsigned int x = ((unsigned int)u) << 16;
    return __builtin_bit_cast(float, x);
}
__device__ __forceinline__ float leakyf(float x) { return fmaxf(x, ALPHA * x); }
__device__ __forceinline__ float ub(unsigned int d, int e) {
    return (float)((d >> (8 * e)) & 0xffu);
}

__device__ __forceinline__ ushort8 cvt8(const float* __restrict__ p) {
    float4v x0 = *(const float4v*)p;
    float4v x1 = *(const float4v*)(p + 4);
    ushort8 r;
    #pragma unroll
    for (int e = 0; e < 4; ++e) { r[e] = f2bf(x0[e]); r[e + 4] = f2bf(x1[e]); }
    return r;
}

// ---------- K-1: adj f32 -> u8 (exact 0/1) ----------
__global__ __launch_bounds__(256) void k_prep(const float* __restrict__ adj,
                                              unsigned char* __restrict__ adj8) {
    size_t base = ((size_t)blockIdx.x * 256 + threadIdx.x) * 8;
    float4v a = *(const float4v*)(adj + base);
    float4v b = *(const float4v*)(adj + base + 4);
    unsigned int lo = 0, hi = 0;
    #pragma unroll
    for (int e = 0; e < 4; ++e) {
        lo |= (a[e] != 0.f ? 1u : 0u) << (8 * e);
        hi |= (b[e] != 0.f ? 1u : 0u) << (8 * e);
    }
    uint2v o; o[0] = lo; o[1] = hi;
    *(uint2v*)(adj8 + base) = o;
}

// ---------- K0: transpose W_att -> WT bf16 (tiny) ----------
__global__ void k_transpose_w(const float* __restrict__ W,
                              unsigned short* __restrict__ WT) {
    int h = blockIdx.x;
    const float* Wh = W + (size_t)h * D_ * HID_;
    unsigned short* WTh = WT + (size_t)h * HID_ * D_;
    for (int idx = threadIdx.x; idx < D_ * HID_; idx += blockDim.x) {
        int d = idx / HID_, o = idx % HID_;
        WTh[o * D_ + d] = f2bf(Wh[idx]);
    }
}

// ---------- K1: wh = fea @ W_att, 2 heads per block ----------
__global__ __launch_bounds__(256) void k_wh(
    const float* __restrict__ fea,
    const unsigned short* __restrict__ WT,
    const float* __restrict__ a_att,
    unsigned short* __restrict__ whT,
    float* __restrict__ e1, float* __restrict__ e2)
{
    int i0 = blockIdx.x << 6;
    int h0 = blockIdx.y * 2;
    int b  = blockIdx.z;

    __shared__ __align__(16) union SmemA {
        struct { unsigned short fa[64 * 72]; unsigned short wt[2][64 * 72]; } s;
        float tr[64 * 65];
    } u;

    int t = threadIdx.x;
    int lane = t & 63;
    int wv = t >> 6;
    int hw = wv & 1;
    int half = wv >> 1;
    int r = lane & 15, q = lane >> 4;
    int ra = t >> 2;
    int cc = (t & 3) * 16;
    int rowbase = half * 32;

    f32x4 acc[2][4] = {};

    const float* fearow = fea + ((size_t)(b * N_ + i0 + ra)) * D_;
    const unsigned short* wt0row = WT + ((size_t)(h0 * 64 + ra)) * D_;
    const unsigned short* wt1row = WT + ((size_t)((h0 + 1) * 64 + ra)) * D_;

    for (int d0 = 0; d0 < D_; d0 += 64) {
        *(ushort8*)&u.s.fa[ra * 72 + cc]       = cvt8(fearow + d0 + cc);
        *(ushort8*)&u.s.fa[ra * 72 + cc + 8]   = cvt8(fearow + d0 + cc + 8);
        *(ushort8*)&u.s.wt[0][ra * 72 + cc]     = *(const ushort8*)(wt0row + d0 + cc);
        *(ushort8*)&u.s.wt[0][ra * 72 + cc + 8] = *(const ushort8*)(wt0row + d0 + cc + 8);
        *(ushort8*)&u.s.wt[1][ra * 72 + cc]     = *(const ushort8*)(wt1row + d0 + cc);
        *(ushort8*)&u.s.wt[1][ra * 72 + cc + 8] = *(const ushort8*)(wt1row + d0 + cc + 8);
        __syncthreads();
        #pragma unroll
        for (int k0 = 0; k0 < 64; k0 += 32) {
            bf16x8 a0 = *(const bf16x8*)&u.s.fa[(rowbase + r) * 72 + k0 + q * 8];
            bf16x8 a1 = *(const bf16x8*)&u.s.fa[(rowbase + 16 + r) * 72 + k0 + q * 8];
            #pragma unroll
            for (int f = 0; f < 4; ++f) {
                bf16x8 bb = *(const bf16x8*)&u.s.wt[hw][(16 * f + r) * 72 + k0 + q * 8];
                acc[0][f] = __builtin_amdgcn_mfma_f32_16x16x32_bf16(a0, bb, acc[0][f], 0, 0, 0);
                acc[1][f] = __builtin_amdgcn_mfma_f32_16x16x32_bf16(a1, bb, acc[1][f], 0, 0, 0);
            }
        }
        __syncthreads();
    }

    float a1v[4], a2v[4];
    #pragma unroll
    for (int f = 0; f < 4; ++f) {
        a1v[f] = a_att[(h0 + hw) * 128 + 16 * f + r];
        a2v[f] = a_att[(h0 + hw) * 128 + 64 + 16 * f + r];
    }
    #pragma unroll
    for (int m = 0; m < 2; ++m) {
        #pragma unroll
        for (int rr = 0; rr < 4; ++rr) {
            float s1 = 0.f, s2 = 0.f;
            #pragma unroll
            for (int f = 0; f < 4; ++f) { s1 += acc[m][f][rr] * a1v[f]; s2 += acc[m][f][rr] * a2v[f]; }
            #pragma unroll
            for (int sh = 1; sh < 16; sh <<= 1) {
                s1 += __shfl_xor(s1, sh, 64);
                s2 += __shfl_xor(s2, sh, 64);
            }
            if (r == 0) {
                int i = i0 + rowbase + 16 * m + 4 * q + rr;
                size_t idx = ((size_t)(b * H_ + h0 + hw)) * N_ + i;
                e1[idx] = s1 * LOG2E; e2[idx] = s2 * LOG2E;
            }
        }
    }

    #pragma unroll
    for (int hh = 0; hh < 2; ++hh) {
        __syncthreads();
        if (hw == hh) {
            #pragma unroll
            for (int m = 0; m < 2; ++m)
                #pragma unroll
                for (int f = 0; f < 4; ++f)
                    #pragma unroll
                    for (int rr = 0; rr < 4; ++rr)
                        u.tr[(16 * f + r) * 65 + rowbase + 16 * m + 4 * q + rr] = acc[m][f][rr];
        }
        __syncthreads();
        {
            int o = t >> 2;
            int ch = (t & 3) * 16;
            unsigned short tmp[16];
            #pragma unroll
            for (int e = 0; e < 16; ++e) tmp[e] = f2bf(u.tr[o * 65 + ch + e]);
            ushort8* dst = (ushort8*)(whT + (((size_t)(b * H_ + h0 + hh) * 64 + o)) * N_ + i0 + ch);
            dst[0] = *(ushort8*)&tmp[0];
            dst[1] = *(ushort8*)&tmp[8];
        }
    }
}

// ---------- K2: maxE2[bh] = max_j e2[bh][j] ----------
__global__ __launch_bounds__(256) void k_maxe2(const float* __restrict__ e2,
                                               float* __restrict__ mx) {
    int bh = blockIdx.x;
    int t = threadIdx.x;
    const float* row = e2 + (size_t)bh * N_;
    float M = NEGBIG;
    #pragma unroll
    for (int it = 0; it < N_ / 256; ++it) M = fmaxf(M, row[it * 256 + t]);
    #pragma unroll
    for (int s = 1; s < 64; s <<= 1) M = fmaxf(M, __shfl_xor(M, s, 64));
    __shared__ float red[4];
    if ((t & 63) == 0) red[t >> 6] = M;
    __syncthreads();
    if (t == 0) mx[bh] = fmaxf(fmaxf(red[0], red[1]), fmaxf(red[2], red[3]));
}

// ---------- K3 (new): 2 heads x 128 rows per 512-thr block; adj via LDS ----------
// VMEM-issue-minimized: per thread per tile: 2x b128 whT + 1x b128 adj loads;
// epilogue via LDS transpose -> 4x b128 stores/thread.
template<int JPER>
__global__ __launch_bounds__(512, 4) void k_pv2(
    const unsigned char* __restrict__ adj8,
    const unsigned short* __restrict__ whT,   // [B][H][64][N] bf16
    const float* __restrict__ e1g, const float* __restrict__ e2g,
    const float* __restrict__ maxE2,
    unsigned short* __restrict__ x_part,      // [S][B][N][512] bf16
    float* __restrict__ zPart)                // [S][16][N] f32
{
    constexpr int NT = JPER / 64;
    int s  = blockIdx.x;
    int i0 = blockIdx.y << 7;                 // 128 rows
    int z  = blockIdx.z;                      // b*4 + hpair
    int b  = z >> 2;
    int h0 = (z & 3) * 2;
    int bh0 = b * H_ + h0;
    int jBeg = s * JPER;

    __shared__ __align__(16) union {
        struct {
            unsigned short wt[2][2][4096];    // [buf][head][64x64] swizzled
            unsigned char  adjl[2][128 * 80]; // [buf][row][80-pad]
            unsigned int   tv[2][JPER];       // packed bf16 {2^e2, 2^(a*e2)}
        } m;
        unsigned short epi[128][136];
    } u;

    int t = threadIdx.x;
    int lane = t & 63;
    int w = t >> 6;                           // wave 0..7
    int hw = w & 1;                           // head within pair
    int rw = (w >> 1) * 32;                   // row base of this wave
    int r = lane & 15, q = lane >> 4;
    int bh = bh0 + hw;

    // per-row softmax prefactors (2 rows per lane)
    int ir0 = i0 + rw + r, ir1 = ir0 + 16;
    float mxv = maxE2[bh];
    float e1_0 = e1g[(size_t)bh * N_ + ir0];
    float e1_1 = e1g[(size_t)bh * N_ + ir1];
    float m0 = leakyf(e1_0 + mxv), m1 = leakyf(e1_1 + mxv);
    float sI0 = __builtin_amdgcn_exp2f(e1_0 - m0);
    float uI0 = __builtin_amdgcn_exp2f(ALPHA * e1_0 - m0);
    float sI1 = __builtin_amdgcn_exp2f(e1_1 - m1);
    float uI1 = __builtin_amdgcn_exp2f(ALPHA * e1_1 - m1);

    // staging assignments
    int sh = t >> 8;                          // head this thread stages
    int so = (t & 255) >> 2;                  // o-row
    int sj = (t & 3) * 16;                    // j-col chunk
    const unsigned short* wsrc = whT + ((size_t)(bh0 + sh) * 64 + so) * N_ + jBeg + sj;
    int wof0 = sh * 4096 + so * 64 + (sj ^ ((so & 7) << 3));
    int wof1 = sh * 4096 + so * 64 + ((sj + 8) ^ ((so & 7) << 3));
    int ar = t >> 2, ac = (t & 3) * 16;
    const unsigned char* asrc = adj8 + ((size_t)(b * N_ + i0 + ar)) * N_ + jBeg + ac;
    int aof = ar * 80 + ac;

    int swzr = (r & 7) << 3;
    int koff0 = (8 * q) ^ swzr;
    int koff1 = (32 + 8 * q) ^ swzr;

    bf16x8 ones;
    #pragma unroll
    for (int e = 0; e < 8; ++e) ones[e] = (__bf16)1.0f;

    f32x4 acc[2][4] = {};
    f32x4 accz[2] = {};

    ushort8 wA, wB;   // whT stage regs (1 tile ahead)
    uint4v  aR;       // adj stage reg

#define LOADSTG(tile) do {                                        \
        wA = *(const ushort8*)(wsrc + (tile) * 64);               \
        wB = *(const ushort8*)(wsrc + (tile) * 64 + 8);           \
        aR = *(const uint4v*)(asrc + (tile) * 64);                \
    } while (0)

    // prologue: tv tables, tile0 -> buf0, tile1 -> regs
    for (int jj = t; jj < 2 * JPER; jj += 512) {
        int hh = jj >= JPER ? 1 : 0;
        int j = jj - hh * JPER;
        float ev = e2g[(size_t)(bh0 + hh) * N_ + jBeg + j];
        unsigned int pk = (unsigned int)f2bf(__builtin_amdgcn_exp2f(ev))
                        | ((unsigned int)f2bf(__builtin_amdgcn_exp2f(ALPHA * ev)) << 16);
        u.m.tv[hh][j] = pk;
    }
    LOADSTG(0);
    asm volatile("s_waitcnt vmcnt(0)" ::: "memory");
    *(ushort8*)((unsigned short*)u.m.wt[0] + wof0) = wA;
    *(ushort8*)((unsigned short*)u.m.wt[0] + wof1) = wB;
    *(uint4v*)&u.m.adjl[0][aof] = aR;
    if (NT > 1) LOADSTG(1);
    asm volatile("s_waitcnt lgkmcnt(0)" ::: "memory");
    __builtin_amdgcn_s_barrier();

    #pragma unroll 2
    for (int t8 = 0; t8 < NT; ++t8) {
        const int p = t8 & 1;
        // write tile t8+1 (regs) into other buffer; then prefetch t8+2
        if (t8 + 1 < NT) {
            asm volatile("s_waitcnt vmcnt(0)" ::: "memory");
            *(ushort8*)((unsigned short*)u.m.wt[p ^ 1] + wof0) = wA;
            *(ushort8*)((unsigned short*)u.m.wt[p ^ 1] + wof1) = wB;
            *(uint4v*)&u.m.adjl[p ^ 1][aof] = aR;
        }
        if (t8 + 2 < NT) LOADSTG(t8 + 2);

        // tv slices (bf16-packed), shared by both m-rows
        const unsigned int* tvp = &u.m.tv[hw][t8 * 64 + q * 8];
        uint4v ta0 = *(const uint4v*)(tvp);
        uint4v ta1 = *(const uint4v*)(tvp + 4);
        uint4v tb0 = *(const uint4v*)(tvp + 32);
        uint4v tb1 = *(const uint4v*)(tvp + 36);
        // adj bytes from LDS (2 rows x 2 k-halves)
        const unsigned char* ab = &u.m.adjl[p][(rw + r) * 80 + q * 8];
        uint2v a0 = *(const uint2v*)(ab);
        uint2v a1 = *(const uint2v*)(ab + 32);
        uint2v a2 = *(const uint2v*)(ab + 16 * 80);
        uint2v a3 = *(const uint2v*)(ab + 16 * 80 + 32);

        bf16x8 pa00, pa01, pa10, pa11;
        #pragma unroll
        for (int e = 0; e < 4; ++e) {
            float tt, vv;
            unsigned int uu;
            uu = ta0[e];
            tt = __builtin_bit_cast(float, uu << 16);
            vv = __builtin_bit_cast(float, uu & 0xffff0000u);
            pa00[e] = (__bf16)(fmaxf(sI0 * tt, uI0 * vv) * ub(a0[0], e));
            pa10[e] = (__bf16)(fmaxf(sI1 * tt, uI1 * vv) * ub(a2[0], e));
            uu = ta1[e];
            tt = __builtin_bit_cast(float, uu << 16);
            vv = __builtin_bit_cast(float, uu & 0xffff0000u);
            pa00[e + 4] = (__bf16)(fmaxf(sI0 * tt, uI0 * vv) * ub(a0[1], e));
            pa10[e + 4] = (__bf16)(fmaxf(sI1 * tt, uI1 * vv) * ub(a2[1], e));
            uu = tb0[e];
            tt = __builtin_bit_cast(float, uu << 16);
            vv = __builtin_bit_cast(float, uu & 0xffff0000u);
            pa01[e] = (__bf16)(fmaxf(sI0 * tt, uI0 * vv) * ub(a1[0], e));
            pa11[e] = (__bf16)(fmaxf(sI1 * tt, uI1 * vv) * ub(a3[0], e));
            uu = tb1[e];
            tt = __builtin_bit_cast(float, uu << 16);
            vv = __builtin_bit_cast(float, uu & 0xffff0000u);
            pa01[e + 4] = (__bf16)(fmaxf(sI0 * tt, uI0 * vv) * ub(a1[1], e));
            pa11[e + 4] = (__bf16)(fmaxf(sI1 * tt, uI1 * vv) * ub(a3[1], e));
        }

        const unsigned short* Wb = (const unsigned short*)u.m.wt[p] + hw * 4096;
        bf16x8 bb;
        #pragma unroll
        for (int f = 0; f < 4; ++f) {
            bb = *(const bf16x8*)&Wb[f * 1024 + r * 64 + koff0];
            acc[0][f] = __builtin_amdgcn_mfma_f32_16x16x32_bf16(pa00, bb, acc[0][f], 0, 0, 0);
            acc[1][f] = __builtin_amdgcn_mfma_f32_16x16x32_bf16(pa10, bb, acc[1][f], 0, 0, 0);
        }
        accz[0] = __builtin_amdgcn_mfma_f32_16x16x32_bf16(pa00, ones, accz[0], 0, 0, 0);
        accz[1] = __builtin_amdgcn_mfma_f32_16x16x32_bf16(pa10, ones, accz[1], 0, 0, 0);
        #pragma unroll
        for (int f = 0; f < 4; ++f) {
            bb = *(const bf16x8*)&Wb[f * 1024 + r * 64 + koff1];
            acc[0][f] = __builtin_amdgcn_mfma_f32_16x16x32_bf16(pa01, bb, acc[0][f], 0, 0, 0);
            acc[1][f] = __builtin_amdgcn_mfma_f32_16x16x32_bf16(pa11, bb, acc[1][f], 0, 0, 0);
        }
        accz[0] = __builtin_amdgcn_mfma_f32_16x16x32_bf16(pa01, ones, accz[0], 0, 0, 0);
        accz[1] = __builtin_amdgcn_mfma_f32_16x16x32_bf16(pa11, ones, accz[1], 0, 0, 0);

        asm volatile("s_waitcnt lgkmcnt(0)" ::: "memory");
        __builtin_amdgcn_s_barrier();
    }
#undef LOADSTG

    // zPart (small, direct)
    if (r == 0) {
        #pragma unroll
        for (int mR = 0; mR < 2; ++mR)
            #pragma unroll
            for (int rr = 0; rr < 4; ++rr) {
                int i = i0 + rw + mR * 16 + 4 * q + rr;
                zPart[((size_t)(s * 16 + bh)) * N_ + i] = accz[mR][rr];
            }
    }

    // epilogue: acc -> LDS (bf16) -> coalesced b128 stores
    #pragma unroll
    for (int mR = 0; mR < 2; ++mR)
        #pragma unroll
        for (int f = 0; f < 4; ++f)
            #pragma unroll
            for (int rr = 0; rr < 4; ++rr)
                u.epi[rw + mR * 16 + 4 * q + rr][hw * 64 + 16 * f + r] = f2bf(acc[mR][f][rr]);
    __syncthreads();
    {
        int tr = t >> 2;
        int ch = (t & 3) * 32;
        const ushort8* src = (const ushort8*)&u.epi[tr][ch];
        ushort8 v0 = src[0], v1 = src[1], v2 = src[2], v3 = src[3];
        unsigned short* dst = x_part
            + ((size_t)s * (B_ * N_) + (size_t)b * N_ + i0 + tr) * 512 + h0 * 64 + ch;
        ((ushort8*)dst)[0] = v0;
        ((ushort8*)dst)[1] = v1;
        ((ushort8*)dst)[2] = v2;
        ((ushort8*)dst)[3] = v3;
    }
}

// ---------- K3 (fallback for S<4): round-9 kernel ----------
template<int JPER>
__global__ __launch_bounds__(256, 4) void k_pv1(
    const unsigned char* __restrict__ adj8,
    const unsigned short* __restrict__ whT,
    const float* __restrict__ e1g, const float* __restrict__ e2g,
    const float* __restrict__ maxE2,
    unsigned short* __restrict__ x_part,
    float* __restrict__ zPart)
{
    constexpr int NT = JPER / 64;
    int s  = blockIdx.x;
    int i0 = blockIdx.y << 7;
    int bh = blockIdx.z;
    int h = bh & 7, b = bh >> 3;
    int jBeg = s * JPER;

    __shared__ __align__(16) unsigned short wt_lds[2][64 * 64];
    __shared__ float tE[JPER];
    __shared__ float vE[JPER];

    int t = threadIdx.x;
    int lane = t & 63;
    int wv = t >> 6;
    int r = lane & 15, q = lane >> 4;

    int ir0 = i0 + wv * 32 + r;
    int ir1 = ir0 + 16;
    float mx = maxE2[bh];
    float e1_0 = e1g[(size_t)bh * N_ + ir0];
    float e1_1 = e1g[(size_t)bh * N_ + ir1];
    float m0 = leakyf(e1_0 + mx), m1 = leakyf(e1_1 + mx);
    float sI0 = __builtin_amdgcn_exp2f(e1_0 - m0);
    float uI0 = __builtin_amdgcn_exp2f(ALPHA * e1_0 - m0);
    float sI1 = __builtin_amdgcn_exp2f(e1_1 - m1);
    float uI1 = __builtin_amdgcn_exp2f(ALPHA * e1_1 - m1);

    const float* e2p = e2g + (size_t)bh * N_ + jBeg;
    const unsigned char* ap0 = adj8 + ((size_t)(b * N_ + ir0)) * N_ + jBeg + q * 8;
    const unsigned char* ap1 = ap0 + (size_t)16 * N_;

    int c0 = t, c1 = t + 256;
    const unsigned short* wsrc0 =
        whT + ((size_t)bh * 64 + (c0 >> 3)) * N_ + jBeg + (c0 & 7) * 8;
    const unsigned short* wsrc1 =
        whT + ((size_t)bh * 64 + (c1 >> 3)) * N_ + jBeg + (c1 & 7) * 8;
    int woff0 = (c0 * 8) ^ (((c0 >> 3) & 7) << 3);
    int woff1 = (c1 * 8) ^ (((c1 >> 3) & 7) << 3);

    int swz = (r & 7) << 3;
    int koff0 = (8 * q) ^ swz;
    int koff1 = (32 + 8 * q) ^ swz;

    bf16x8 ones;
    #pragma unroll
    for (int e = 0; e < 8; ++e) ones[e] = (__bf16)1.0f;

    f32x4 acc[2][4] = {};
    f32x4 accz[2] = {};

    uint2v aA[4], aB[4];
    ushort8 wN0, wN1;

#define LOADADJ(A, tile) do {                                                   \
        const unsigned char* p0 = ap0 + (tile) * 64;                            \
        const unsigned char* p1 = ap1 + (tile) * 64;                            \
        A[0] = *(const uint2v*)(p0);      A[1] = *(const uint2v*)(p0 + 32);     \
        A[2] = *(const uint2v*)(p1);      A[3] = *(const uint2v*)(p1 + 32);     \
    } while (0)
#define LOADW(tile) do {                                                        \
        wN0 = *(const ushort8*)(wsrc0 + (tile) * 64);                           \
        wN1 = *(const ushort8*)(wsrc1 + (tile) * 64);                           \
    } while (0)

    for (int jj = t; jj < JPER; jj += 256) {
        float ev = e2p[jj];
        tE[jj] = __builtin_amdgcn_exp2f(ev);
        vE[jj] = __builtin_amdgcn_exp2f(ALPHA * ev);
    }
    LOADW(0);
    *(ushort8*)&wt_lds[0][woff0] = wN0;
    *(ushort8*)&wt_lds[0][woff1] = wN1;
    if (NT > 1) LOADW(1);
    LOADADJ(aA, 0);
    if (NT > 1) LOADADJ(aB, 1);
    asm volatile("s_waitcnt lgkmcnt(0)" ::: "memory");
    __builtin_amdgcn_s_barrier();

    auto pgen = [&](const uint2v& alo, const uint2v& ahi, float sI, float uI,
                    const float4v& t0, const float4v& t1,
                    const float4v& t2, const float4v& t3,
                    const float4v& v0, const float4v& v1,
                    const float4v& v2, const float4v& v3,
                    bf16x8& pa0, bf16x8& pa1) {
        #pragma unroll
        for (int e = 0; e < 4; ++e) {
            pa0[e]     = (__bf16)(fmaxf(sI * t0[e], uI * v0[e]) * ub(alo[0], e));
            pa0[e + 4] = (__bf16)(fmaxf(sI * t1[e], uI * v1[e]) * ub(alo[1], e));
            pa1[e]     = (__bf16)(fmaxf(sI * t2[e], uI * v2[e]) * ub(ahi[0], e));
            pa1[e + 4] = (__bf16)(fmaxf(sI * t3[e], uI * v3[e]) * ub(ahi[1], e));
        }
    };

    #pragma unroll 2
    for (int t8 = 0; t8 < NT; ++t8) {
        const int cur = t8 & 1;
        if (t8 + 1 < NT) {
            *(ushort8*)&wt_lds[cur ^ 1][woff0] = wN0;
            *(ushort8*)&wt_lds[cur ^ 1][woff1] = wN1;
        }
        if (t8 + 2 < NT) LOADW(t8 + 2);

        const float* tb = &tE[t8 * 64 + q * 8];
        const float* vb = &vE[t8 * 64 + q * 8];
        float4v t0 = *(const float4v*)(tb),      t1 = *(const float4v*)(tb + 4);
        float4v t2 = *(const float4v*)(tb + 32), t3 = *(const float4v*)(tb + 36);
        float4v v0 = *(const float4v*)(vb),      v1 = *(const float4v*)(vb + 4);
        float4v v2 = *(const float4v*)(vb + 32), v3 = *(const float4v*)(vb + 36);

        bf16x8 pa00, pa01, pa10, pa11;
        if (cur == 0) {
            pgen(aA[0], aA[1], sI0, uI0, t0, t1, t2, t3, v0, v1, v2, v3, pa00, pa01);
            pgen(aA[2], aA[3], sI1, uI1, t0, t1, t2, t3, v0, v1, v2, v3, pa10, pa11);
        } else {
            pgen(aB[0], aB[1], sI0, uI0, t0, t1, t2, t3, v0, v1, v2, v3, pa00, pa01);
            pgen(aB[2], aB[3], sI1, uI1, t0, t1, t2, t3, v0, v1, v2, v3, pa10, pa11);
        }
        if (t8 + 2 < NT) {
            if (cur == 0) LOADADJ(aA, t8 + 2);
            else          LOADADJ(aB, t8 + 2);
        }

        const unsigned short* Wb = wt_lds[cur];
        bf16x8 bb0[4], bb1[4];
        #pragma unroll
        for (int f = 0; f < 4; ++f) {
            bb0[f] = *(const bf16x8*)&Wb[f * 1024 + r * 64 + koff0];
            bb1[f] = *(const bf16x8*)&Wb[f * 1024 + r * 64 + koff1];
        }
        #pragma unroll
        for (int f = 0; f < 4; ++f) {
            acc[0][f] = __builtin_amdgcn_mfma_f32_16x16x32_bf16(pa00, bb0[f], acc[0][f], 0, 0, 0);
            acc[1][f] = __builtin_amdgcn_mfma_f32_16x16x32_bf16(pa10, bb0[f], acc[1][f], 0, 0, 0);
        }
        accz[0] = __builtin_amdgcn_mfma_f32_16x16x32_bf16(pa00, ones, accz[0], 0, 0, 0);
        accz[1] = __builtin_amdgcn_mfma_f32_16x16x32_bf16(pa10, ones, accz[1], 0, 0, 0);
        #pragma unroll
        for (int f = 0; f < 4; ++f) {
            acc[0][f] = __builtin_amdgcn_mfma_f32_16x16x32_bf16(pa01, bb1[f], acc[0][f], 0, 0, 0);
            acc[1][f] = __builtin_amdgcn_mfma_f32_16x16x32_bf16(pa11, bb1[f], acc[1][f], 0, 0, 0);
        }
        accz[0] = __builtin_amdgcn_mfma_f32_16x16x32_bf16(pa01, ones, accz[0], 0, 0, 0);
        accz[1] = __builtin_amdgcn_mfma_f32_16x16x32_bf16(pa11, ones, accz[1], 0, 0, 0);

        asm volatile("s_waitcnt lgkmcnt(0)" ::: "memory");
        __builtin_amdgcn_s_barrier();
    }
#undef LOADADJ
#undef LOADW

    unsigned short* xp = x_part + ((size_t)s * (B_ * N_) + (size_t)b * N_) * 512 + h * 64;
    #pragma unroll
    for (int mR = 0; mR < 2; ++mR) {
        #pragma unroll
        for (int f = 0; f < 4; ++f) {
            #pragma unroll
            for (int rr = 0; rr < 4; ++rr) {
                int i = i0 + wv * 32 + mR * 16 + 4 * q + rr;
                xp[(size_t)i * 512 + 16 * f + r] = f2bf(acc[mR][f][rr]);
            }
        }
        if (r == 0) {
            #pragma unroll
            for (int rr = 0; rr < 4; ++rr) {
                int i = i0 + wv * 32 + mR * 16 + 4 * q + rr;
                zPart[((size_t)(s * 16 + bh)) * N_ + i] = accz[mR][rr];
            }
        }
    }
}

// ---------- K4: x = elu(sum_s part / Z); wh2 = x @ W_last ----------
__global__ __launch_bounds__(256) void k_wh2(
    const unsigned short* __restrict__ x_part,
    const float* __restrict__ zPart,
    const float* __restrict__ W_last,
    const float* __restrict__ a_last,
    float* __restrict__ wh2, float* __restrict__ g1, float* __restrict__ g2,
    int S)
{
    int idx = blockIdx.x * 4 + (threadIdx.x >> 6);
    int lane = threadIdx.x & 63;
    int b = idx >> 11, n = idx & (N_ - 1);
    float a0 = 0.f, a1 = 0.f;
    #pragma unroll
    for (int it = 0; it < 8; ++it) {
        int k = it * 64 + lane;
        float xv = 0.f, zv = 0.f;
        for (int s = 0; s < S; ++s) {
            xv += bf2f(x_part[((size_t)s * (B_ * N_) + idx) * 512 + k]);
            zv += zPart[((size_t)(s * 16 + b * 8 + it)) * N_ + n];
        }
        float x = (zv > 0.f) ? xv / zv : 0.f;
        x = x > 0.f ? x : expm1f(x);
        float2v wl = *(const float2v*)(W_last + k * 2);
        a0 += x * wl[0];
        a1 += x * wl[1];
    }
    #pragma unroll
    for (int s = 1; s < 64; s <<= 1) {
        a0 += __shfl_xor(a0, s, 64);
        a1 += __shfl_xor(a1, s, 64);
    }
    if (lane == 0) {
        wh2[idx * 2] = a0; wh2[idx * 2 + 1] = a1;
        g1[idx] = (a0 * a_last[0] + a1 * a_last[1]) * LOG2E;
        g2[idx] = (a0 * a_last[2] + a1 * a_last[3]) * LOG2E;
    }
}

// ---------- K5: final attention + elu ----------
__global__ __launch_bounds__(256) void k_out(
    const unsigned char* __restrict__ adj8,
    const float* __restrict__ wh2,
    const float* __restrict__ g1, const float* __restrict__ g2,
    float* __restrict__ out)
{
    int idx = blockIdx.x * 4 + (threadIdx.x >> 6);
    int lane = threadIdx.x & 63;
    int b = idx >> 11;
    float gi = g1[idx];
    const unsigned char* arow = adj8 + (size_t)idx * N_;
    const float* g2b = g2 + (size_t)b * N_;
    const float* wh2b = wh2 + (size_t)b * N_ * 2;

    float ep[32];
    float M = NEGBIG;
    #pragma unroll
    for (int it = 0; it < 8; ++it) {
        int j = it * 256 + lane * 4;
        unsigned int d = *(const unsigned int*)(arow + j);
        float4v s4 = *(const float4v*)(g2b + j);
        #pragma unroll
        for (int e = 0; e < 4; ++e) {
            float l = leakyf(gi + s4[e]);
            float v = ((d >> (8 * e)) & 0xffu) ? l : NEGBIG;
            ep[it * 4 + e] = v;
            M = fmaxf(M, v);
        }
    }
    #pragma unroll
    for (int s = 1; s < 64; s <<= 1) M = fmaxf(M, __shfl_xor(M, s, 64));

    float Z = 0.f, A0 = 0.f, A1 = 0.f;
    #pragma unroll
    for (int it = 0; it < 8; ++it) {
        int j = it * 256 + lane * 4;
        float4v wA = *(const float4v*)(wh2b + 2 * j);
        float4v wB = *(const float4v*)(wh2b + 2 * j + 4);
        #pragma unroll
        for (int e = 0; e < 4; ++e) {
            float p = __builtin_amdgcn_exp2f(ep[it * 4 + e] - M);
            Z += p;
            float w0 = (e < 2) ? wA[2 * e] : wB[2 * (e - 2)];
            float w1 = (e < 2) ? wA[2 * e + 1] : wB[2 * (e - 2) + 1];
            A0 += p * w0;
            A1 += p * w1;
        }
    }
    #pragma unroll
    for (int s = 1; s < 64; s <<= 1) {
        Z += __shfl_xor(Z, s, 64);
        A0 += __shfl_xor(A0, s, 64);
        A1 += __shfl_xor(A1, s, 64);
    }
    if (lane == 0) {
        float o0 = A0 / Z, o1 = A1 / Z;
        o0 = o0 > 0.f ? o0 : expm1f(o0);
        o1 = o1 > 0.f ? o1 : expm1f(o1);
        float2v ov; ov[0] = o0; ov[1] = o1;
        *(float2v*)(out + idx * 2) = ov;
    }
}

extern "C" void kernel_launch(void* const* d_in, const int* in_sizes, int n_in,
                              void* d_out, int out_size, void* d_ws, size_t ws_size,
                              hipStream_t stream) {
    const float* fea    = (const float*)d_in[0];
    const float* adj    = (const float*)d_in[1];
    const float* W_att  = (const float*)d_in[2];
    const float* a_att  = (const float*)d_in[3];
    const float* W_last = (const float*)d_in[4];
    const float* a_last = (const float*)d_in[5];

    char* ws = (char*)d_ws;
    float* e1  = (float*)(ws + 0);
    float* e2  = (float*)(ws + 131072);
    float* mxE = (float*)(ws + 262144);
    float* wh2 = (float*)(ws + 262400);
    float* g1  = (float*)(ws + 295168);
    float* g2  = (float*)(ws + 311552);
    unsigned short* WT  = (unsigned short*)(ws + 327936);
    unsigned short* whT = (unsigned short*)(ws + 590080);
    float* zPart = (float*)(ws + 4784384);
    unsigned char* adj8 = (unsigned char*)(ws + 5308672);
    unsigned short* x_part = (unsigned short*)(ws + 13697280);

    const size_t BASE = 13697280ULL, XPART = 4194304ULL;
    int S = (ws_size >= BASE + 4 * XPART) ? 4
          : (ws_size >= BASE + 2 * XPART) ? 2 : 1;

    k_prep<<<dim3(B_ * N_ * N_ / 2048), dim3(256), 0, stream>>>(adj, adj8);
    k_transpose_w<<<dim3(H_), dim3(256), 0, stream>>>(W_att, WT);
    k_wh<<<dim3(N_ / 64, H_ / 2, B_), dim3(256), 0, stream>>>(
        fea, WT, a_att, whT, e1, e2);
    k_maxe2<<<dim3(B_ * H_), dim3(256), 0, stream>>>(e2, mxE);
    if (S == 4)
        k_pv2<512><<<dim3(4, N_ / 128, B_ * 4), dim3(512), 0, stream>>>(
            adj8, whT, e1, e2, mxE, x_part, zPart);
    else if (S == 2)
        k_pv1<1024><<<dim3(2, N_ / 128, B_ * H_), dim3(256), 0, stream>>>(
            adj8, whT, e1, e2, mxE, x_part, zPart);
    else
        k_pv1<2048><<<dim3(1, N_ / 128, B_ * H_), dim3(256), 0, stream>>>(
            adj8, whT, e1, e2, mxE, x_part, zPart);
    k_wh2<<<dim3(B_ * N_ / 4), dim3(256), 0, stream>>>(
        x_part, zPart, W_last, a_last, wh2, g1, g2, S);
    k_out<<<dim3(B_ * N_ / 4), dim3(256), 0, stream>>>(
        adj8, wh2, g1, g2, (float*)d_out);
}

// Round 14
// 85.834 us; speedup vs baseline: 1.0601x; 1.0597x over previous
//
#include <hip/hip_runtime.h>
#include <hip/hip_bf16.h>
#include <cstdint>
#include <cstddef>

#define B_ 2
#define N_ 2048
#define D_ 256
#define H_ 8
#define HID_ 64
#define EN_ 2
#define ALPHA 0.2f
#define NEGBIG (-3.0e38f)
#define LOG2E 1.4426950408889634f

typedef __bf16 bf16x8 __attribute__((ext_vector_type(8)));
typedef float f32x4 __attribute__((ext_vector_type(4)));
typedef unsigned short ushort8 __attribute__((ext_vector_type(8)));
typedef float float4v __attribute__((ext_vector_type(4)));
typedef float float2v __attribute__((ext_vector_type(2)));
typedef unsigned int uint2v __attribute__((ext_vector_type(2)));
typedef unsigned int uint4v __attribute__((ext_vector_type(4)));

__device__ __forceinline__ unsigned short f2bf(float f) {
    unsigned int u = __builtin_bit_cast(unsigned int, f);
    unsigned int r = u + 0x7FFFu + ((u >> 16) & 1u);  // RNE
    return (unsigned short)(r >> 16);
}
__device__ __forceinline__ float bf2f(unsigned short u) {
    unsigned int x = ((unsigned int)u) << 16;
    return __builtin_bit_cast(float, x);
}
__device__ __forceinline__ float leakyf(float x) { return fmaxf(x, ALPHA * x); }
__device__ __forceinline__ float ub(unsigned int d, int e) {
    return (float)((d >> (8 * e)) & 0xffu);
}

__device__ __forceinline__ ushort8 cvt8(const float* __restrict__ p) {
    float4v x0 = *(const float4v*)p;
    float4v x1 = *(const float4v*)(p + 4);
    ushort8 r;
    #pragma unroll
    for (int e = 0; e < 4; ++e) { r[e] = f2bf(x0[e]); r[e + 4] = f2bf(x1[e]); }
    return r;
}

// ---------- K-1: adj f32 -> u8 (exact 0/1) ----------
__global__ __launch_bounds__(256) void k_prep(const float* __restrict__ adj,
                                              unsigned char* __restrict__ adj8) {
    size_t base = ((size_t)blockIdx.x * 256 + threadIdx.x) * 8;
    float4v a = *(const float4v*)(adj + base);
    float4v b = *(const float4v*)(adj + base + 4);
    unsigned int lo = 0, hi = 0;
    #pragma unroll
    for (int e = 0; e < 4; ++e) {
        lo |= (a[e] != 0.f ? 1u : 0u) << (8 * e);
        hi |= (b[e] != 0.f ? 1u : 0u) << (8 * e);
    }
    uint2v o; o[0] = lo; o[1] = hi;
    *(uint2v*)(adj8 + base) = o;
}

// ---------- K0: transpose W_att -> WT bf16 (tiny) ----------
__global__ void k_transpose_w(const float* __restrict__ W,
                              unsigned short* __restrict__ WT) {
    int h = blockIdx.x;
    const float* Wh = W + (size_t)h * D_ * HID_;
    unsigned short* WTh = WT + (size_t)h * HID_ * D_;
    for (int idx = threadIdx.x; idx < D_ * HID_; idx += blockDim.x) {
        int d = idx / HID_, o = idx % HID_;
        WTh[o * D_ + d] = f2bf(Wh[idx]);
    }
}

// ---------- K1: wh = fea @ W_att, 2 heads per block ----------
__global__ __launch_bounds__(256) void k_wh(
    const float* __restrict__ fea,
    const unsigned short* __restrict__ WT,
    const float* __restrict__ a_att,
    unsigned short* __restrict__ whT,
    float* __restrict__ e1, float* __restrict__ e2)
{
    int i0 = blockIdx.x << 6;
    int h0 = blockIdx.y * 2;
    int b  = blockIdx.z;

    __shared__ __align__(16) union SmemA {
        struct { unsigned short fa[64 * 72]; unsigned short wt[2][64 * 72]; } s;
        float tr[64 * 65];
    } u;

    int t = threadIdx.x;
    int lane = t & 63;
    int wv = t >> 6;
    int hw = wv & 1;
    int half = wv >> 1;
    int r = lane & 15, q = lane >> 4;
    int ra = t >> 2;
    int cc = (t & 3) * 16;
    int rowbase = half * 32;

    f32x4 acc[2][4] = {};

    const float* fearow = fea + ((size_t)(b * N_ + i0 + ra)) * D_;
    const unsigned short* wt0row = WT + ((size_t)(h0 * 64 + ra)) * D_;
    const unsigned short* wt1row = WT + ((size_t)((h0 + 1) * 64 + ra)) * D_;

    for (int d0 = 0; d0 < D_; d0 += 64) {
        *(ushort8*)&u.s.fa[ra * 72 + cc]       = cvt8(fearow + d0 + cc);
        *(ushort8*)&u.s.fa[ra * 72 + cc + 8]   = cvt8(fearow + d0 + cc + 8);
        *(ushort8*)&u.s.wt[0][ra * 72 + cc]     = *(const ushort8*)(wt0row + d0 + cc);
        *(ushort8*)&u.s.wt[0][ra * 72 + cc + 8] = *(const ushort8*)(wt0row + d0 + cc + 8);
        *(ushort8*)&u.s.wt[1][ra * 72 + cc]     = *(const ushort8*)(wt1row + d0 + cc);
        *(ushort8*)&u.s.wt[1][ra * 72 + cc + 8] = *(const ushort8*)(wt1row + d0 + cc + 8);
        __syncthreads();
        #pragma unroll
        for (int k0 = 0; k0 < 64; k0 += 32) {
            bf16x8 a0 = *(const bf16x8*)&u.s.fa[(rowbase + r) * 72 + k0 + q * 8];
            bf16x8 a1 = *(const bf16x8*)&u.s.fa[(rowbase + 16 + r) * 72 + k0 + q * 8];
            #pragma unroll
            for (int f = 0; f < 4; ++f) {
                bf16x8 bb = *(const bf16x8*)&u.s.wt[hw][(16 * f + r) * 72 + k0 + q * 8];
                acc[0][f] = __builtin_amdgcn_mfma_f32_16x16x32_bf16(a0, bb, acc[0][f], 0, 0, 0);
                acc[1][f] = __builtin_amdgcn_mfma_f32_16x16x32_bf16(a1, bb, acc[1][f], 0, 0, 0);
            }
        }
        __syncthreads();
    }

    float a1v[4], a2v[4];
    #pragma unroll
    for (int f = 0; f < 4; ++f) {
        a1v[f] = a_att[(h0 + hw) * 128 + 16 * f + r];
        a2v[f] = a_att[(h0 + hw) * 128 + 64 + 16 * f + r];
    }
    #pragma unroll
    for (int m = 0; m < 2; ++m) {
        #pragma unroll
        for (int rr = 0; rr < 4; ++rr) {
            float s1 = 0.f, s2 = 0.f;
            #pragma unroll
            for (int f = 0; f < 4; ++f) { s1 += acc[m][f][rr] * a1v[f]; s2 += acc[m][f][rr] * a2v[f]; }
            #pragma unroll
            for (int sh = 1; sh < 16; sh <<= 1) {
                s1 += __shfl_xor(s1, sh, 64);
                s2 += __shfl_xor(s2, sh, 64);
            }
            if (r == 0) {
                int i = i0 + rowbase + 16 * m + 4 * q + rr;
                size_t idx = ((size_t)(b * H_ + h0 + hw)) * N_ + i;
                e1[idx] = s1 * LOG2E; e2[idx] = s2 * LOG2E;
            }
        }
    }

    #pragma unroll
    for (int hh = 0; hh < 2; ++hh) {
        __syncthreads();
        if (hw == hh) {
            #pragma unroll
            for (int m = 0; m < 2; ++m)
                #pragma unroll
                for (int f = 0; f < 4; ++f)
                    #pragma unroll
                    for (int rr = 0; rr < 4; ++rr)
                        u.tr[(16 * f + r) * 65 + rowbase + 16 * m + 4 * q + rr] = acc[m][f][rr];
        }
        __syncthreads();
        {
            int o = t >> 2;
            int ch = (t & 3) * 16;
            unsigned short tmp[16];
            #pragma unroll
            for (int e = 0; e < 16; ++e) tmp[e] = f2bf(u.tr[o * 65 + ch + e]);
            ushort8* dst = (ushort8*)(whT + (((size_t)(b * H_ + h0 + hh) * 64 + o)) * N_ + i0 + ch);
            dst[0] = *(ushort8*)&tmp[0];
            dst[1] = *(ushort8*)&tmp[8];
        }
    }
}

// ---------- K2: maxE2[bh] = max_j e2[bh][j] ----------
__global__ __launch_bounds__(256) void k_maxe2(const float* __restrict__ e2,
                                               float* __restrict__ mx) {
    int bh = blockIdx.x;
    int t = threadIdx.x;
    const float* row = e2 + (size_t)bh * N_;
    float M = NEGBIG;
    #pragma unroll
    for (int it = 0; it < N_ / 256; ++it) M = fmaxf(M, row[it * 256 + t]);
    #pragma unroll
    for (int s = 1; s < 64; s <<= 1) M = fmaxf(M, __shfl_xor(M, s, 64));
    __shared__ float red[4];
    if ((t & 63) == 0) red[t >> 6] = M;
    __syncthreads();
    if (t == 0) mx[bh] = fmaxf(fmaxf(red[0], red[1]), fmaxf(red[2], red[3]));
}

// ---------- K3: 2 heads x 128 rows per 512-thr block; adj via LDS ----------
// VMEM-issue-minimized: per thread per tile: 2x b128 whT + 1x b128 adj loads;
// epilogue via LDS transpose -> 4x b128 stores/thread.
template<int JPER>
__global__ __launch_bounds__(512, 4) void k_pv2(
    const unsigned char* __restrict__ adj8,
    const unsigned short* __restrict__ whT,   // [B][H][64][N] bf16
    const float* __restrict__ e1g, const float* __restrict__ e2g,
    const float* __restrict__ maxE2,
    unsigned short* __restrict__ x_part,      // [S][B][N][512] bf16
    float* __restrict__ zPart)                // [S][16][N] f32
{
    constexpr int NT = JPER / 64;
    int s  = blockIdx.x;
    int i0 = blockIdx.y << 7;                 // 128 rows
    int z  = blockIdx.z;                      // b*4 + hpair
    int b  = z >> 2;
    int h0 = (z & 3) * 2;
    int bh0 = b * H_ + h0;
    int jBeg = s * JPER;

    __shared__ __align__(16) union {
        struct {
            unsigned short wt[2][2][4096];    // [buf][head][64x64] swizzled
            unsigned char  adjl[2][128 * 80]; // [buf][row][80-pad]
            unsigned int   tv[2][JPER];       // packed bf16 {2^e2, 2^(a*e2)}
        } m;
        unsigned short epi[128][136];
    } u;

    int t = threadIdx.x;
    int lane = t & 63;
    int w = t >> 6;                           // wave 0..7
    int hw = w & 1;                           // head within pair
    int rw = (w >> 1) * 32;                   // row base of this wave
    int r = lane & 15, q = lane >> 4;
    int bh = bh0 + hw;

    // per-row softmax prefactors (2 rows per lane)
    int ir0 = i0 + rw + r, ir1 = ir0 + 16;
    float mxv = maxE2[bh];
    float e1_0 = e1g[(size_t)bh * N_ + ir0];
    float e1_1 = e1g[(size_t)bh * N_ + ir1];
    float m0 = leakyf(e1_0 + mxv), m1 = leakyf(e1_1 + mxv);
    float sI0 = __builtin_amdgcn_exp2f(e1_0 - m0);
    float uI0 = __builtin_amdgcn_exp2f(ALPHA * e1_0 - m0);
    float sI1 = __builtin_amdgcn_exp2f(e1_1 - m1);
    float uI1 = __builtin_amdgcn_exp2f(ALPHA * e1_1 - m1);

    // staging assignments
    int sh = t >> 8;                          // head this thread stages
    int so = (t & 255) >> 2;                  // o-row
    int sj = (t & 3) * 16;                    // j-col chunk
    const unsigned short* wsrc = whT + ((size_t)(bh0 + sh) * 64 + so) * N_ + jBeg + sj;
    int wof0 = sh * 4096 + so * 64 + (sj ^ ((so & 7) << 3));
    int wof1 = sh * 4096 + so * 64 + ((sj + 8) ^ ((so & 7) << 3));
    int ar = t >> 2, ac = (t & 3) * 16;
    const unsigned char* asrc = adj8 + ((size_t)(b * N_ + i0 + ar)) * N_ + jBeg + ac;
    int aof = ar * 80 + ac;

    int swzr = (r & 7) << 3;
    int koff0 = (8 * q) ^ swzr;
    int koff1 = (32 + 8 * q) ^ swzr;

    bf16x8 ones;
    #pragma unroll
    for (int e = 0; e < 8; ++e) ones[e] = (__bf16)1.0f;

    f32x4 acc[2][4] = {};
    f32x4 accz[2] = {};

    ushort8 wA, wB;   // whT stage regs (1 tile ahead)
    uint4v  aR;       // adj stage reg

#define LOADSTG(tile) do {                                        \
        wA = *(const ushort8*)(wsrc + (tile) * 64);               \
        wB = *(const ushort8*)(wsrc + (tile) * 64 + 8);           \
        aR = *(const uint4v*)(asrc + (tile) * 64);                \
    } while (0)

    // prologue: tv tables, tile0 -> buf0, tile1 -> regs
    for (int jj = t; jj < 2 * JPER; jj += 512) {
        int hh = jj >= JPER ? 1 : 0;
        int j = jj - hh * JPER;
        float ev = e2g[(size_t)(bh0 + hh) * N_ + jBeg + j];
        unsigned int pk = (unsigned int)f2bf(__builtin_amdgcn_exp2f(ev))
                        | ((unsigned int)f2bf(__builtin_amdgcn_exp2f(ALPHA * ev)) << 16);
        u.m.tv[hh][j] = pk;
    }
    LOADSTG(0);
    asm volatile("s_waitcnt vmcnt(0)" ::: "memory");
    *(ushort8*)((unsigned short*)u.m.wt[0] + wof0) = wA;
    *(ushort8*)((unsigned short*)u.m.wt[0] + wof1) = wB;
    *(uint4v*)&u.m.adjl[0][aof] = aR;
    if (NT > 1) LOADSTG(1);
    asm volatile("s_waitcnt lgkmcnt(0)" ::: "memory");
    __builtin_amdgcn_s_barrier();

    #pragma unroll 2
    for (int t8 = 0; t8 < NT; ++t8) {
        const int p = t8 & 1;
        // write tile t8+1 (regs) into other buffer; then prefetch t8+2
        if (t8 + 1 < NT) {
            asm volatile("s_waitcnt vmcnt(0)" ::: "memory");
            *(ushort8*)((unsigned short*)u.m.wt[p ^ 1] + wof0) = wA;
            *(ushort8*)((unsigned short*)u.m.wt[p ^ 1] + wof1) = wB;
            *(uint4v*)&u.m.adjl[p ^ 1][aof] = aR;
        }
        if (t8 + 2 < NT) LOADSTG(t8 + 2);

        // tv slices (bf16-packed), shared by both m-rows
        const unsigned int* tvp = &u.m.tv[hw][t8 * 64 + q * 8];
        uint4v ta0 = *(const uint4v*)(tvp);
        uint4v ta1 = *(const uint4v*)(tvp + 4);
        uint4v tb0 = *(const uint4v*)(tvp + 32);
        uint4v tb1 = *(const uint4v*)(tvp + 36);
        // adj bytes from LDS (2 rows x 2 k-halves)
        const unsigned char* ab = &u.m.adjl[p][(rw + r) * 80 + q * 8];
        uint2v a0 = *(const uint2v*)(ab);
        uint2v a1 = *(const uint2v*)(ab + 32);
        uint2v a2 = *(const uint2v*)(ab + 16 * 80);
        uint2v a3 = *(const uint2v*)(ab + 16 * 80 + 32);

        bf16x8 pa00, pa01, pa10, pa11;
        #pragma unroll
        for (int e = 0; e < 4; ++e) {
            float tt, vv;
            unsigned int uu;
            uu = ta0[e];
            tt = __builtin_bit_cast(float, uu << 16);
            vv = __builtin_bit_cast(float, uu & 0xffff0000u);
            pa00[e] = (__bf16)(fmaxf(sI0 * tt, uI0 * vv) * ub(a0[0], e));
            pa10[e] = (__bf16)(fmaxf(sI1 * tt, uI1 * vv) * ub(a2[0], e));
            uu = ta1[e];
            tt = __builtin_bit_cast(float, uu << 16);
            vv = __builtin_bit_cast(float, uu & 0xffff0000u);
            pa00[e + 4] = (__bf16)(fmaxf(sI0 * tt, uI0 * vv) * ub(a0[1], e));
            pa10[e + 4] = (__bf16)(fmaxf(sI1 * tt, uI1 * vv) * ub(a2[1], e));
            uu = tb0[e];
            tt = __builtin_bit_cast(float, uu << 16);
            vv = __builtin_bit_cast(float, uu & 0xffff0000u);
            pa01[e] = (__bf16)(fmaxf(sI0 * tt, uI0 * vv) * ub(a1[0], e));
            pa11[e] = (__bf16)(fmaxf(sI1 * tt, uI1 * vv) * ub(a3[0], e));
            uu = tb1[e];
            tt = __builtin_bit_cast(float, uu << 16);
            vv = __builtin_bit_cast(float, uu & 0xffff0000u);
            pa01[e + 4] = (__bf16)(fmaxf(sI0 * tt, uI0 * vv) * ub(a1[1], e));
            pa11[e + 4] = (__bf16)(fmaxf(sI1 * tt, uI1 * vv) * ub(a3[1], e));
        }

        const unsigned short* Wb = (const unsigned short*)u.m.wt[p] + hw * 4096;
        bf16x8 bb;
        #pragma unroll
        for (int f = 0; f < 4; ++f) {
            bb = *(const bf16x8*)&Wb[f * 1024 + r * 64 + koff0];
            acc[0][f] = __builtin_amdgcn_mfma_f32_16x16x32_bf16(pa00, bb, acc[0][f], 0, 0, 0);
            acc[1][f] = __builtin_amdgcn_mfma_f32_16x16x32_bf16(pa10, bb, acc[1][f], 0, 0, 0);
        }
        accz[0] = __builtin_amdgcn_mfma_f32_16x16x32_bf16(pa00, ones, accz[0], 0, 0, 0);
        accz[1] = __builtin_amdgcn_mfma_f32_16x16x32_bf16(pa10, ones, accz[1], 0, 0, 0);
        #pragma unroll
        for (int f = 0; f < 4; ++f) {
            bb = *(const bf16x8*)&Wb[f * 1024 + r * 64 + koff1];
            acc[0][f] = __builtin_amdgcn_mfma_f32_16x16x32_bf16(pa01, bb, acc[0][f], 0, 0, 0);
            acc[1][f] = __builtin_amdgcn_mfma_f32_16x16x32_bf16(pa11, bb, acc[1][f], 0, 0, 0);
        }
        accz[0] = __builtin_amdgcn_mfma_f32_16x16x32_bf16(pa01, ones, accz[0], 0, 0, 0);
        accz[1] = __builtin_amdgcn_mfma_f32_16x16x32_bf16(pa11, ones, accz[1], 0, 0, 0);

        asm volatile("s_waitcnt lgkmcnt(0)" ::: "memory");
        __builtin_amdgcn_s_barrier();
    }
#undef LOADSTG

    // zPart (small, direct)
    if (r == 0) {
        #pragma unroll
        for (int mR = 0; mR < 2; ++mR)
            #pragma unroll
            for (int rr = 0; rr < 4; ++rr) {
                int i = i0 + rw + mR * 16 + 4 * q + rr;
                zPart[((size_t)(s * 16 + bh)) * N_ + i] = accz[mR][rr];
            }
    }

    // epilogue: acc -> LDS (bf16) -> coalesced b128 stores
    #pragma unroll
    for (int mR = 0; mR < 2; ++mR)
        #pragma unroll
        for (int f = 0; f < 4; ++f)
            #pragma unroll
            for (int rr = 0; rr < 4; ++rr)
                u.epi[rw + mR * 16 + 4 * q + rr][hw * 64 + 16 * f + r] = f2bf(acc[mR][f][rr]);
    __syncthreads();
    {
        int tr = t >> 2;
        int ch = (t & 3) * 32;
        const ushort8* src = (const ushort8*)&u.epi[tr][ch];
        ushort8 v0 = src[0], v1 = src[1], v2 = src[2], v3 = src[3];
        unsigned short* dst = x_part
            + ((size_t)s * (B_ * N_) + (size_t)b * N_ + i0 + tr) * 512 + h0 * 64 + ch;
        ((ushort8*)dst)[0] = v0;
        ((ushort8*)dst)[1] = v1;
        ((ushort8*)dst)[2] = v2;
        ((ushort8*)dst)[3] = v3;
    }
}

// ---------- K4: x = elu(sum_s part / Z); wh2 = x @ W_last ----------
__global__ __launch_bounds__(256) void k_wh2(
    const unsigned short* __restrict__ x_part,
    const float* __restrict__ zPart,
    const float* __restrict__ W_last,
    const float* __restrict__ a_last,
    float* __restrict__ wh2, float* __restrict__ g1, float* __restrict__ g2,
    int S)
{
    int idx = blockIdx.x * 4 + (threadIdx.x >> 6);
    int lane = threadIdx.x & 63;
    int b = idx >> 11, n = idx & (N_ - 1);
    float a0 = 0.f, a1 = 0.f;
    #pragma unroll
    for (int it = 0; it < 8; ++it) {
        int k = it * 64 + lane;
        float xv = 0.f, zv = 0.f;
        for (int s = 0; s < S; ++s) {
            xv += bf2f(x_part[((size_t)s * (B_ * N_) + idx) * 512 + k]);
            zv += zPart[((size_t)(s * 16 + b * 8 + it)) * N_ + n];
        }
        float x = (zv > 0.f) ? xv / zv : 0.f;
        x = x > 0.f ? x : expm1f(x);
        float2v wl = *(const float2v*)(W_last + k * 2);
        a0 += x * wl[0];
        a1 += x * wl[1];
    }
    #pragma unroll
    for (int s = 1; s < 64; s <<= 1) {
        a0 += __shfl_xor(a0, s, 64);
        a1 += __shfl_xor(a1, s, 64);
    }
    if (lane == 0) {
        wh2[idx * 2] = a0; wh2[idx * 2 + 1] = a1;
        g1[idx] = (a0 * a_last[0] + a1 * a_last[1]) * LOG2E;
        g2[idx] = (a0 * a_last[2] + a1 * a_last[3]) * LOG2E;
    }
}

// ---------- K5: final attention + elu ----------
__global__ __launch_bounds__(256) void k_out(
    const unsigned char* __restrict__ adj8,
    const float* __restrict__ wh2,
    const float* __restrict__ g1, const float* __restrict__ g2,
    float* __restrict__ out)
{
    int idx = blockIdx.x * 4 + (threadIdx.x >> 6);
    int lane = threadIdx.x & 63;
    int b = idx >> 11;
    float gi = g1[idx];
    const unsigned char* arow = adj8 + (size_t)idx * N_;
    const float* g2b = g2 + (size_t)b * N_;
    const float* wh2b = wh2 + (size_t)b * N_ * 2;

    float ep[32];
    float M = NEGBIG;
    #pragma unroll
    for (int it = 0; it < 8; ++it) {
        int j = it * 256 + lane * 4;
        unsigned int d = *(const unsigned int*)(arow + j);
        float4v s4 = *(const float4v*)(g2b + j);
        #pragma unroll
        for (int e = 0; e < 4; ++e) {
            float l = leakyf(gi + s4[e]);
            float v = ((d >> (8 * e)) & 0xffu) ? l : NEGBIG;
            ep[it * 4 + e] = v;
            M = fmaxf(M, v);
        }
    }
    #pragma unroll
    for (int s = 1; s < 64; s <<= 1) M = fmaxf(M, __shfl_xor(M, s, 64));

    float Z = 0.f, A0 = 0.f, A1 = 0.f;
    #pragma unroll
    for (int it = 0; it < 8; ++it) {
        int j = it * 256 + lane * 4;
        float4v wA = *(const float4v*)(wh2b + 2 * j);
        float4v wB = *(const float4v*)(wh2b + 2 * j + 4);
        #pragma unroll
        for (int e = 0; e < 4; ++e) {
            float p = __builtin_amdgcn_exp2f(ep[it * 4 + e] - M);
            Z += p;
            float w0 = (e < 2) ? wA[2 * e] : wB[2 * (e - 2)];
            float w1 = (e < 2) ? wA[2 * e + 1] : wB[2 * (e - 2) + 1];
            A0 += p * w0;
            A1 += p * w1;
        }
    }
    #pragma unroll
    for (int s = 1; s < 64; s <<= 1) {
        Z += __shfl_xor(Z, s, 64);
        A0 += __shfl_xor(A0, s, 64);
        A1 += __shfl_xor(A1, s, 64);
    }
    if (lane == 0) {
        float o0 = A0 / Z, o1 = A1 / Z;
        o0 = o0 > 0.f ? o0 : expm1f(o0);
        o1 = o1 > 0.f ? o1 : expm1f(o1);
        float2v ov; ov[0] = o0; ov[1] = o1;
        *(float2v*)(out + idx * 2) = ov;
    }
}

extern "C" void kernel_launch(void* const* d_in, const int* in_sizes, int n_in,
                              void* d_out, int out_size, void* d_ws, size_t ws_size,
                              hipStream_t stream) {
    const float* fea    = (const float*)d_in[0];
    const float* adj    = (const float*)d_in[1];
    const float* W_att  = (const float*)d_in[2];
    const float* a_att  = (const float*)d_in[3];
    const float* W_last = (const float*)d_in[4];
    const float* a_last = (const float*)d_in[5];

    char* ws = (char*)d_ws;
    float* e1  = (float*)(ws + 0);
    float* e2  = (float*)(ws + 131072);
    float* mxE = (float*)(ws + 262144);
    float* wh2 = (float*)(ws + 262400);
    float* g1  = (float*)(ws + 295168);
    float* g2  = (float*)(ws + 311552);
    unsigned short* WT  = (unsigned short*)(ws + 327936);
    unsigned short* whT = (unsigned short*)(ws + 590080);
    float* zPart = (float*)(ws + 4784384);
    unsigned char* adj8 = (unsigned char*)(ws + 5308672);
    unsigned short* x_part = (unsigned short*)(ws + 13697280);

    const size_t BASE = 13697280ULL, XPART = 4194304ULL;
    int S = (ws_size >= BASE + 2 * XPART) ? 2 : 1;

    k_prep<<<dim3(B_ * N_ * N_ / 2048), dim3(256), 0, stream>>>(adj, adj8);
    k_transpose_w<<<dim3(H_), dim3(256), 0, stream>>>(W_att, WT);
    k_wh<<<dim3(N_ / 64, H_ / 2, B_), dim3(256), 0, stream>>>(
        fea, WT, a_att, whT, e1, e2);
    k_maxe2<<<dim3(B_ * H_), dim3(256), 0, stream>>>(e2, mxE);
    if (S == 2)
        k_pv2<1024><<<dim3(2, N_ / 128, B_ * 4), dim3(512), 0, stream>>>(
            adj8, whT, e1, e2, mxE, x_part, zPart);
    else
        k_pv2<2048><<<dim3(1, N_ / 128, B_ * 4), dim3(512), 0, stream>>>(
            adj8, whT, e1, e2, mxE, x_part, zPart);
    k_wh2<<<dim3(B_ * N_ / 4), dim3(256), 0, stream>>>(
        x_part, zPart, W_last, a_last, wh2, g1, g2, S);
    k_out<<<dim3(B_ * N_ / 4), dim3(256), 0, stream>>>(
        adj8, wh2, g1, g2, (float*)d_out);
}